// Round 13
// baseline (177.590 us; speedup 1.0000x reference)
//
#include <hip/hip_runtime.h>
#include <hip/hip_bf16.h>

#define BATCH 2
#define SEQ 2048
#define DM 512
#define NH 8
#define DHD 64
#define QP 256
#define KVP 341
#define DQKPAD 96
#define MROWS 4096   // BATCH*SEQ

// bf16 arena element offsets (x, W_o, LN params only)
#define OFF_X     0
#define OFF_WO    2932224
#define OFF_QG    3194368
#define OFF_QB    3194624
#define OFF_KG    3194880
#define OFF_KB    3195221

// transposed-weight arena element offsets ([N][K])
#define T_DQ   0        // [256][512]
#define T_DKV  131072   // [384][512] (n>=341 zero)
#define T_KR   327680   // [64][512]
#define T_UQ   360448   // [512][256]
#define T_QR   491520   // [64][256]
#define T_UKV  507904   // [1024][384] (k>=341 zero)
#define T_TOT  901120

#define NW_X   2097152
#define NW_WO  262144
#define NW_PAR 1194

// prep work groups (8 elems each)
#define G_X   262144
#define G_WO  32768
#define G_PAR 150
#define G_WT  112640
#define G_TOT (G_X + G_WO + G_PAR + G_WT)

#define NSPLIT 4

typedef __bf16 bf16x8 __attribute__((ext_vector_type(8)));
typedef float f32x4 __attribute__((ext_vector_type(4)));
typedef float f32x16 __attribute__((ext_vector_type(16)));
typedef __hip_bfloat16 bf16;
typedef unsigned short u16;
typedef unsigned int u32;

static __device__ __forceinline__ bf16x8 ld_bf8(const bf16* p) {
    return __builtin_bit_cast(bf16x8, *(const uint4*)p);
}
static __device__ __forceinline__ u32 cvtpk(float lo, float hi) {
    u32 r;
    asm("v_cvt_pk_bf16_f32 %0, %1, %2" : "=v"(r) : "v"(lo), "v"(hi));
    return r;
}

// async global->LDS, 16B per lane; LDS dest = wave-uniform base + lane*16
#define GL16(gp, lp) __builtin_amdgcn_global_load_lds( \
    (const __attribute__((address_space(1))) void*)(gp), \
    (__attribute__((address_space(3))) void*)(lp), 16, 0, 0)

// ---------- prep: dtype-flag + convert x/W_o/params + weight transposes (8-wide) ----------
__global__ __launch_bounds__(256) void prep(
    const void* px, const void* pwdq, const void* pwuq, const void* pwqr,
    const void* pwdkv, const void* pwukv, const void* pwkr, const void* pwo,
    const void* pqg, const void* pqb, const void* pkg, const void* pkb,
    u16* __restrict__ arena, u16* __restrict__ WT, int* __restrict__ flagp)
{
    __shared__ int cnt;
    if (threadIdx.x == 0) cnt = 0;
    __syncthreads();
    int bad = 0;
    const u16* xs = (const u16*)px;
    for (int i = threadIdx.x; i < 2048; i += 256) {
        u16 u = xs[i];
        int e = (u >> 7) & 0xFF;
        if (u != 0 && (e < 90 || e > 164)) bad++;
    }
    #pragma unroll
    for (int m2 = 1; m2 < 64; m2 <<= 1) bad += __shfl_xor(bad, m2);
    if ((threadIdx.x & 63) == 0) atomicAdd(&cnt, bad);
    __syncthreads();
    const int f = (cnt > 256) ? 1 : 0;   // 1 => inputs are fp32
    if (blockIdx.x == 0 && threadIdx.x == 0) *flagp = f;

    int gid = blockIdx.x * 256 + threadIdx.x;
    if (gid >= G_TOT) return;

    auto rdu = [&](const void* s, int i) -> u16 {
        if (f) return __builtin_bit_cast(u16, __float2bfloat16(((const float*)s)[i]));
        return ((const u16*)s)[i];
    };

    if (gid < G_X + G_WO) {
        const void* src = (gid < G_X) ? px : pwo;
        int base = (gid < G_X) ? OFF_X : OFF_WO;
        int i = (gid < G_X) ? gid : gid - G_X;
        u16 out[8];
        if (f) {
            const float* s = (const float*)src + i * 8;
            #pragma unroll
            for (int j = 0; j < 8; ++j) out[j] = __builtin_bit_cast(u16, __float2bfloat16(s[j]));
        } else {
            *(uint4*)out = ((const uint4*)src)[i];
        }
        *(uint4*)&arena[base + i * 8] = *(uint4*)out;
    } else if (gid < G_X + G_WO + G_PAR) {
        int i0 = (gid - G_X - G_WO) * 8;
        for (int j = 0; j < 8; ++j) {
            int i = i0 + j;
            if (i >= NW_PAR) break;
            if (i < 256)      arena[OFF_QG + i]         = rdu(pqg, i);
            else if (i < 512) arena[OFF_QB + (i - 256)] = rdu(pqb, i - 256);
            else if (i < 853) arena[OFF_KG + (i - 512)] = rdu(pkg, i - 512);
            else              arena[OFF_KB + (i - 853)] = rdu(pkb, i - 853);
        }
    } else {
        int loc = (gid - (G_X + G_WO + G_PAR)) * 8;   // 8 consecutive: same n, k0..k0+7
        const void* src; int n, k0, sN, klim, nok;
        if (loc < T_DKV)      { int l = loc;          n = l >> 9; k0 = l & 511; src = pwdq;  sN = 256;  klim = 512; nok = 1; }
        else if (loc < T_KR)  { int l = loc - T_DKV;  n = l >> 9; k0 = l & 511; src = pwdkv; sN = 341;  klim = 512; nok = (n < 341); }
        else if (loc < T_UQ)  { int l = loc - T_KR;   n = l >> 9; k0 = l & 511; src = pwkr;  sN = 64;   klim = 512; nok = 1; }
        else if (loc < T_QR)  { int l = loc - T_UQ;   n = l >> 8; k0 = l & 255; src = pwuq;  sN = 512;  klim = 256; nok = 1; }
        else if (loc < T_UKV) { int l = loc - T_QR;   n = l >> 8; k0 = l & 255; src = pwqr;  sN = 64;   klim = 256; nok = 1; }
        else                  { int l = loc - T_UKV;  n = l / 384; k0 = l % 384; src = pwukv; sN = 1024; klim = 341; nok = 1; }
        u16 out[8];
        #pragma unroll
        for (int j = 0; j < 8; ++j) {
            int k = k0 + j;
            out[j] = (nok && k < klim) ? rdu(src, k * sN + n) : (u16)0;
        }
        *(uint4*)&WT[loc] = *(uint4*)out;
    }
}

// ---------- rope epilogue: acc holds 64 rope cols for 128 rows; partner via shfl ----------
static __device__ __forceinline__ void rope_epi(
    f32x4 (&acc)[2][4], bf16* __restrict__ dst, int m0, int w, int g, int lr, int tid, bool scaleq)
{
    const float SCv = 0.11785113019775793f;   // 1/sqrt(72)
    #pragma unroll
    for (int mt = 0; mt < 2; ++mt)
    #pragma unroll
    for (int r = 0; r < 4; ++r) {
        int gm = m0 + w * 32 + mt * 16 + g * 4 + r;
        int s = gm & 2047, b = gm >> 11;
        float ang = (float)s * exp2f(-(float)(lr & 3) * 3.3219280948873623f);
        float sn, cs;
        sincosf(ang, &sn, &cs);
        #pragma unroll
        for (int nt = 0; nt < 4; ++nt) {
            float v = acc[mt][nt][r];
            float pt = __shfl_xor(v, 4);
            float o = (lr & 4) ? fmaf(pt, sn, v * cs) : fmaf(-pt, sn, v * cs);
            if (scaleq) o *= SCv;
            int h = (nt * 16 + lr) >> 3, j = lr & 7;
            dst[((size_t)(b * NH + h) * SEQ + s) * DQKPAD + 64 + j] = __float2bfloat16(o);
        }
    }
    // zero pads [72,96) for all 8 heads of these 128 rows
    for (int u = tid; u < 128 * 96; u += 256) {
        int rw = u / 96, rem = u - rw * 96;
        int h = rem / 12, c = rem - h * 12;
        int row = m0 + rw, b2 = row >> 11, s2 = row & 2047;
        *(unsigned int*)&dst[((size_t)(b2 * NH + h) * SEQ + s2) * DQKPAD + 72 + c * 2] = 0u;
    }
}

// ------- 128x64 bf16 MFMA GEMM, BK=64, global_load_lds staging + XOR swizzle -------
// modes: 0 fp32->C0 (n0==640: kr-rope -> kv_k); 1 dual->C0/C0f;
// 3 KV-scatter (K direct, V via LDS transpose); 4 Q-scatter scaled (n0==512: q-rope).
__global__ __launch_bounds__(256) void gemm128(
    const bf16* __restrict__ A, int lda,
    const bf16* __restrict__ BT, int ldb,
    int N, int Kpad, int mode,
    void* __restrict__ C0, int ldc,
    bf16* __restrict__ kv_k, bf16* __restrict__ kv_v,
    const int* __restrict__ flagp, float* __restrict__ C0f)
{
    __shared__ __align__(16) bf16 LB[128 * 64 + 64 * 64];   // Al 16KB | Bl 8KB
    bf16* Al = LB;
    bf16* Bl = LB + 128 * 64;
    const int tid = threadIdx.x;
    const int m0 = blockIdx.y * 128, n0 = blockIdx.x * 64;
    const int lane = tid & 63, w = tid >> 6;
    const int g = lane >> 4, lr = lane & 15;
    f32x4 acc[2][4] = {};
    const int r8 = lane >> 3;
    const int xr8 = ((lane & 7) ^ r8) * 8;     // pre-swizzled source column (elems)
    const int swx = (lr & 7) << 4;             // read-side XOR (bytes)

    for (int k0 = 0; k0 < Kpad; k0 += 64) {
        #pragma unroll
        for (int i = 0; i < 4; ++i)
            GL16(&A[(size_t)(m0 + w * 32 + i * 8 + r8) * lda + k0 + xr8],
                 (char*)Al + w * 4096 + i * 1024);
        #pragma unroll
        for (int i = 0; i < 2; ++i)
            GL16(&BT[(size_t)(n0 + w * 16 + i * 8 + r8) * ldb + k0 + xr8],
                 (char*)Bl + w * 2048 + i * 1024);
        __syncthreads();
        #pragma unroll
        for (int ks = 0; ks < 2; ++ks) {
            const int cs = (ks * 64 + g * 16) ^ swx;
            bf16x8 a0 = ld_bf8((const bf16*)((const char*)Al + (w * 32 + lr) * 128 + cs));
            bf16x8 a1 = ld_bf8((const bf16*)((const char*)Al + (w * 32 + 16 + lr) * 128 + cs));
            #pragma unroll
            for (int nt = 0; nt < 4; ++nt) {
                bf16x8 b = ld_bf8((const bf16*)((const char*)Bl + (nt * 16 + lr) * 128 + cs));
                acc[0][nt] = __builtin_amdgcn_mfma_f32_16x16x32_bf16(a0, b, acc[0][nt], 0, 0, 0);
                acc[1][nt] = __builtin_amdgcn_mfma_f32_16x16x32_bf16(a1, b, acc[1][nt], 0, 0, 0);
            }
        }
        __syncthreads();
    }

    if (mode == 0 && n0 == 640) {       // kr-rope block (unscaled) -> k_attn
        rope_epi(acc, kv_k, m0, w, g, lr, tid, false);
        return;
    }
    if (mode == 4 && n0 == DM) {        // qr-rope block (scaled) -> q_attn
        rope_epi(acc, (bf16*)C0, m0, w, g, lr, tid, true);
        return;
    }
    if (mode == 3 && n0 >= DM) {
        // V block: LDS transpose -> coalesced V^T rows
        const int h = (n0 - DM) >> 6;
        const int b = m0 >> 11, s0 = m0 & 2047;
        bf16* T = LB;   // [64][stride 136]
        #pragma unroll
        for (int mt = 0; mt < 2; ++mt)
        #pragma unroll
        for (int nt = 0; nt < 4; ++nt)
        #pragma unroll
        for (int r = 0; r < 4; ++r) {
            int dv = nt * 16 + lr;
            int sl = w * 32 + mt * 16 + g * 4 + r;
            T[dv * 136 + sl] = __float2bfloat16(acc[mt][nt][r]);
        }
        __syncthreads();
        const int row = tid >> 2, coff = (tid & 3) * 32;
        bf16* dst = &kv_v[((size_t)(b * NH + h) * DHD + row) * SEQ + s0 + coff];
        const bf16* srcp = &T[row * 136 + coff];
        #pragma unroll
        for (int q2 = 0; q2 < 4; ++q2)
            *(uint4*)(dst + q2 * 8) = *(const uint4*)(srcp + q2 * 8);
        return;
    }

    const float SCv = 0.11785113019775793f;
    const int f32o = (mode == 1 && flagp) ? *flagp : 0;
    #pragma unroll
    for (int mt = 0; mt < 2; ++mt)
    #pragma unroll
    for (int nt = 0; nt < 4; ++nt)
    #pragma unroll
    for (int r = 0; r < 4; ++r) {
        int gm = m0 + w * 32 + mt * 16 + g * 4 + r;
        int gn = n0 + nt * 16 + lr;
        float v = acc[mt][nt][r];
        if (mode == 0) {
            ((float*)C0)[(size_t)gm * ldc + gn] = v;
        } else if (mode == 1) {
            if (f32o) C0f[(size_t)gm * ldc + gn] = v;
            else ((bf16*)C0)[(size_t)gm * ldc + gn] = __float2bfloat16(v);
        } else if (mode == 4) {
            int b = gm >> 11, s = gm & 2047;
            int h = gn >> 6, dh = gn & 63;
            ((bf16*)C0)[((size_t)(b * NH + h) * SEQ + s) * DQKPAD + dh] = __float2bfloat16(v * SCv);
        } else { // mode 3 K block: direct scatter [bh][s][96]
            int b = gm >> 11, s = gm & 2047;
            int h = gn >> 6, dh = gn & 63;
            kv_k[((size_t)(b * NH + h) * SEQ + s) * DQKPAD + dh] = __float2bfloat16(v);
        }
    }
}

// ------- merged layernorms, one wave per row -------
__global__ __launch_bounds__(256) void ln_both(
    const float* __restrict__ y,
    const bf16* __restrict__ qg, const bf16* __restrict__ qb,
    const bf16* __restrict__ kg, const bf16* __restrict__ kb,
    bf16* __restrict__ cq, bf16* __restrict__ ckv_b, float* __restrict__ ckv_f,
    bf16* __restrict__ ckvp, const int* __restrict__ flagp)
{
    const int w = threadIdx.x >> 6, lane = threadIdx.x & 63;
    const int blk = blockIdx.x;
    if (blk < 1024) {
        const int row = blk * 4 + w;
        const float* yr = y + (size_t)row * 704;
        float s = 0.f, ss = 0.f;
        for (int i = lane; i < 256; i += 64) { float v = yr[i]; s += v; ss += v * v; }
        #pragma unroll
        for (int m = 1; m < 64; m <<= 1) { s += __shfl_xor(s, m); ss += __shfl_xor(ss, m); }
        float mean = s * (1.f / 256.f);
        float var = ss * (1.f / 256.f) - mean * mean;
        float rstd = rsqrtf(var + 1e-5f);
        for (int i = lane; i < 256; i += 64) {
            float v = (yr[i] - mean) * rstd * __bfloat162float(qg[i]) + __bfloat162float(qb[i]);
            cq[(size_t)row * 256 + i] = __float2bfloat16(v);
        }
    } else {
        const int row = (blk - 1024) * 4 + w;
        const float* yr = y + (size_t)row * 704 + 256;
        const int f32o = *flagp;
        float s = 0.f, ss = 0.f;
        for (int i = lane; i < KVP; i += 64) { float v = yr[i]; s += v; ss += v * v; }
        #pragma unroll
        for (int m = 1; m < 64; m <<= 1) { s += __shfl_xor(s, m); ss += __shfl_xor(ss, m); }
        float mean = s * (1.f / 341.f);
        float var = ss * (1.f / 341.f) - mean * mean;
        float rstd = rsqrtf(var + 1e-5f);
        for (int i = lane; i < KVP; i += 64) {
            float v = (yr[i] - mean) * rstd * __bfloat162float(kg[i]) + __bfloat162float(kb[i]);
            if (f32o) ckv_f[(size_t)row * KVP + i] = v;
            else ckv_b[(size_t)row * KVP + i] = __float2bfloat16(v);
            ckvp[(size_t)row * 384 + i] = __float2bfloat16(v);
        }
        for (int i = KVP + lane; i < 384; i += 64) ckvp[(size_t)row * 384 + i] = __float2bfloat16(0.f);
    }
}

// ---- causal flash attention v4: 32x32 MFMA, 32q/wave, in-register P (T12),
//      XOR-swizzled K/V LDS, split-KV + tile-pairing + defer-max ----
// grid (NSPLIT=4, 8 pairs, 16 bh); block 256 (4 waves x 32 q-rows = 128 q/block).
__global__ __launch_bounds__(256) void attn_v4(
    const bf16* __restrict__ qa, const bf16* __restrict__ ka, const bf16* __restrict__ vat,
    bf16* __restrict__ po, float* __restrict__ mlm, float* __restrict__ mll)
{
    __shared__ __align__(16) bf16 Kl[64][128];   // 64 keys x 96 (swizzled slots)
    __shared__ __align__(16) bf16 Vt[64][128];   // 64 d x 64 keys (swizzled slots)
    const int sp = blockIdx.x, pr = blockIdx.y, bh = blockIdx.z;
    const int tid = threadIdx.x, w = tid >> 6, lane = tid & 63;
    const int q31 = lane & 31, h = lane >> 5, q15 = lane & 15;
    const size_t base = (size_t)bh * SEQ;
    const float L2E = 1.4426950408889634f;
    const bf16* vb = vat + (size_t)bh * DHD * SEQ;

    for (int half = 0; half < 2; ++half) {
        const int t = half ? (15 - pr) : pr;
        const int tb = t * 128;
        const int qrow0w = tb + w * 32;
        const int myq = qrow0w + q31;

        bf16x8 qf[6];
        #pragma unroll
        for (int ks = 0; ks < 6; ++ks)
            qf[ks] = ld_bf8(&qa[(base + myq) * DQKPAD + ks * 16 + h * 8]);

        float m_p = -1e30f, l_p = 0.f;
        f32x16 acc_o0 = {}, acc_o1 = {};
        const int G = 2 * (t + 1);
        const int bs = (G * sp) >> 2, be = (G * (sp + 1)) >> 2;

        for (int gi = bs; gi < be; ++gi) {
            const int j0 = gi * 64;
            __syncthreads();
            for (int u = tid; u < 768; u += 256) {     // K: 64 rows x 12 slots
                int row = u / 12, sl = u % 12;
                *(uint4*)&Kl[row][(sl ^ (row & 15)) * 8] =
                    *(const uint4*)&ka[(base + j0 + row) * DQKPAD + sl * 8];
            }
            for (int u = tid; u < 512; u += 256) {     // V^T: 64 d x 8 slots
                int d = u >> 3, sl = u & 7;
                *(uint4*)&Vt[d][(sl ^ (d & 15)) * 8] =
                    *(const uint4*)&vb[(size_t)d * SEQ + j0 + sl * 8];
            }
            __syncthreads();
            if (j0 > qrow0w + 31) continue;            // fully masked for this wave

            // QK^T swapped: D[key][q], accs[kt] covers keys kt*32..+31
            f32x16 accs0 = {}, accs1 = {};
            #pragma unroll
            for (int ks = 0; ks < 6; ++ks) {
                bf16x8 kf0 = ld_bf8(&Kl[q31][(((ks * 2 + h) ^ q15) * 8)]);
                bf16x8 kf1 = ld_bf8(&Kl[32 + q31][(((ks * 2 + h) ^ q15) * 8)]);
                accs0 = __builtin_amdgcn_mfma_f32_32x32x16_bf16(kf0, qf[ks], accs0, 0, 0, 0);
                accs1 = __builtin_amdgcn_mfma_f32_32x32x16_bf16(kf1, qf[ks], accs1, 0, 0, 0);
            }
            // mask + local max
            float mloc = -1e30f;
            const bool diag = (j0 + 63 > qrow0w);
            #pragma unroll
            for (int r = 0; r < 16; ++r) {
                int rowk = (r & 3) + 8 * (r >> 2) + 4 * h;
                if (diag) {
                    if (j0 + rowk > myq) accs0[r] = -1e30f;
                    if (j0 + 32 + rowk > myq) accs1[r] = -1e30f;
                }
                mloc = fmaxf(mloc, fmaxf(accs0[r], accs1[r]));
            }
            mloc = fmaxf(mloc, __shfl_xor(mloc, 32));

            if (__all(mloc <= m_p + 8.f)) {            // defer-max
                float rs = 0.f;
                #pragma unroll
                for (int r = 0; r < 16; ++r) {
                    float p0 = exp2f((accs0[r] - m_p) * L2E);
                    float p1 = exp2f((accs1[r] - m_p) * L2E);
                    accs0[r] = p0; accs1[r] = p1; rs += p0 + p1;
                }
                rs += __shfl_xor(rs, 32);
                l_p += rs;
            } else {
                float mn = fmaxf(m_p, mloc);
                float alpha = exp2f((m_p - mn) * L2E);
                m_p = mn;
                float rs = 0.f;
                #pragma unroll
                for (int r = 0; r < 16; ++r) {
                    float p0 = exp2f((accs0[r] - mn) * L2E);
                    float p1 = exp2f((accs1[r] - mn) * L2E);
                    accs0[r] = p0; accs1[r] = p1; rs += p0 + p1;
                }
                rs += __shfl_xor(rs, 32);
                l_p = l_p * alpha + rs;
                #pragma unroll
                for (int r = 0; r < 16; ++r) {
                    float ar = __shfl(alpha, (r & 3) + 8 * (r >> 2) + 4 * h);
                    acc_o0[r] *= ar; acc_o1[r] *= ar;
                }
            }

            // P -> A fragments in-register (cvt_pk + permlane32_swap)
            bf16x8 pa[4];
            #pragma unroll
            for (int kt = 0; kt < 2; ++kt) {
                u32 U[8];
                #pragma unroll
                for (int u = 0; u < 8; ++u)
                    U[u] = kt == 0 ? cvtpk(accs0[2 * u], accs0[2 * u + 1])
                                   : cvtpk(accs1[2 * u], accs1[2 * u + 1]);
                asm volatile("v_permlane32_swap_b32 %0, %1" : "+v"(U[0]), "+v"(U[2]));
                asm volatile("v_permlane32_swap_b32 %0, %1" : "+v"(U[1]), "+v"(U[3]));
                asm volatile("v_permlane32_swap_b32 %0, %1" : "+v"(U[4]), "+v"(U[6]));
                asm volatile("v_permlane32_swap_b32 %0, %1" : "+v"(U[5]), "+v"(U[7]));
                u32 w0[4] = {U[0], U[1], U[2], U[3]};
                u32 w1[4] = {U[4], U[5], U[6], U[7]};
                pa[kt * 2]     = __builtin_bit_cast(bf16x8, *(uint4*)w0);
                pa[kt * 2 + 1] = __builtin_bit_cast(bf16x8, *(uint4*)w1);
            }
            // PV: O[q][d] += P x V^T
            #pragma unroll
            for (int ksv = 0; ksv < 4; ++ksv) {
                bf16x8 vf0 = ld_bf8(&Vt[q31][(((ksv * 2 + h) ^ q15) * 8)]);
                bf16x8 vf1 = ld_bf8(&Vt[32 + q31][(((ksv * 2 + h) ^ q15) * 8)]);
                acc_o0 = __builtin_amdgcn_mfma_f32_32x32x16_bf16(pa[ksv], vf0, acc_o0, 0, 0, 0);
                acc_o1 = __builtin_amdgcn_mfma_f32_32x32x16_bf16(pa[ksv], vf1, acc_o1, 0, 0, 0);
            }
        }

        const size_t pb = (size_t)(bh * NSPLIT + sp) * SEQ;
        #pragma unroll
        for (int r = 0; r < 16; ++r) {
            int q = qrow0w + (r & 3) + 8 * (r >> 2) + 4 * h;
            po[(pb + q) * DHD + q31] = __float2bfloat16(acc_o0[r]);
            po[(pb + q) * DHD + 32 + q31] = __float2bfloat16(acc_o1[r]);
        }
        if (lane < 32) {
            mlm[pb + qrow0w + lane] = m_p;
            mll[pb + qrow0w + lane] = l_p;
        }
    }
}

// ---------------- combine split partials -> attn_o [b][s][h*64+d] ----------------
__global__ __launch_bounds__(256) void attn_combine(
    const bf16* __restrict__ po, const float* __restrict__ mlm, const float* __restrict__ mll,
    bf16* __restrict__ ao)
{
    int id = blockIdx.x * 256 + threadIdx.x;   // 16*2048*8 = 262144
    int bh = id >> 14;
    int rem = id & 16383;
    int q = rem >> 3, dc = (rem & 7) * 8;
    const float L2E = 1.4426950408889634f;
    size_t mlb = (size_t)bh * NSPLIT * SEQ + q;
    float ms[NSPLIT], ls[NSPLIT];
    #pragma unroll
    for (int s = 0; s < NSPLIT; ++s) { ms[s] = mlm[mlb + (size_t)s * SEQ]; ls[s] = mll[mlb + (size_t)s * SEQ]; }
    float M = -1e30f;
    #pragma unroll
    for (int s = 0; s < NSPLIT; ++s) M = fmaxf(M, ms[s]);
    float wsc[NSPLIT]; float L = 0.f;
    #pragma unroll
    for (int s = 0; s < NSPLIT; ++s) { wsc[s] = exp2f((ms[s] - M) * L2E); L += wsc[s] * ls[s]; }
    float o[8] = {};
    #pragma unroll
    for (int s = 0; s < NSPLIT; ++s) {
        if (ls[s] <= 0.f) continue;
        bf16x8 pv = ld_bf8(&po[((size_t)(bh * NSPLIT + s) * SEQ + q) * DHD + dc]);
        #pragma unroll
        for (int j = 0; j < 8; ++j) o[j] += wsc[s] * (float)pv[j];
    }
    float invL = 1.f / L;
    int b = bh >> 3, h = bh & 7;
    __bf16 tmp[8];
    #pragma unroll
    for (int j = 0; j < 8; ++j) tmp[j] = (__bf16)(o[j] * invL);
    *(uint4*)&ao[((size_t)(b * SEQ) + q) * DM + h * DHD + dc] = *(uint4*)tmp;
}

extern "C" void kernel_launch(void* const* d_in, const int* in_sizes, int n_in,
                              void* d_out, int out_size, void* d_ws, size_t ws_size,
                              hipStream_t stream) {
    char* ws = (char*)d_ws;
    bf16* AR      = (bf16*)(ws + 0);              // arena: x | W_o | params
    float* ml_m   = (float*)(ws + 0);             // alias x region (dead after x-gemm), 1MB
    float* ml_l   = (float*)(ws + 1048576);       // 1MB
    bf16* WT      = (bf16*)(ws + 6391296);        // transposed weights (1,802,240 B)
    int*  flagp   = (int*)(ws + 8193536);
    float* y      = (float*)(ws + 8194048);       // fused x-proj out [4096][704] fp32
    bf16* cq      = (bf16*)(ws + 19728384);       // [4096][256]
    bf16* ckvp    = (bf16*)(ws + 21825536);       // [4096][384]
    bf16* q_attn  = (bf16*)(ws + 26019840);
    bf16* k_attn  = (bf16*)(ws + 32311296);
    bf16* v_attnT = (bf16*)(ws + 38602752);
    bf16* attn_o  = (bf16*)(ws + 42797056);
    bf16* po      = (bf16*)(ws + 50331648);       // 4-split partials, 16,777,216 B

    const bf16* xb  = AR + OFF_X;
    const bf16* W_o = AR + OFF_WO;
    const bf16* qg  = AR + OFF_QG;
    const bf16* qb_ = AR + OFF_QB;
    const bf16* kg  = AR + OFF_KG;
    const bf16* kb  = AR + OFF_KB;

    bf16*  out_b = (bf16*)d_out;
    float* out_f = (float*)d_out;
    bf16*  ckv_b = out_b + (size_t)MROWS * DM;
    float* ckv_f = out_f + (size_t)MROWS * DM;

    dim3 blk(256);
    // 1) prep: flag + convert + weight transposes (8-wide)
    prep<<<dim3((G_TOT + 255) / 256), blk, 0, stream>>>(
        d_in[0], d_in[1], d_in[2], d_in[3], d_in[4], d_in[5],
        d_in[6], d_in[7], d_in[8], d_in[9], d_in[10], d_in[11],
        (u16*)AR, (u16*)WT, flagp);
    // 2) fused x-proj [dq|dkv|kr] N=704 (n0==640 block does kr-rope -> k_attn)
    gemm128<<<dim3(11, 32), blk, 0, stream>>>(xb, DM, WT + T_DQ, DM, 704, DM, 0, y, 704, k_attn, nullptr, nullptr, nullptr);
    // 3) merged layernorms
    ln_both<<<dim3(2048), blk, 0, stream>>>(y, qg, qb_, kg, kb, cq, ckv_b, ckv_f, ckvp, flagp);
    // 4) fused cq up-proj [uq|qr] N=576, scaled Q (n0==512 block does q-rope)
    gemm128<<<dim3(9, 32), blk, 0, stream>>>(cq, QP, WT + T_UQ, QP, 576, QP, 4, q_attn, 0, nullptr, nullptr, nullptr, nullptr);
    // 5) kv up-proj (K scatter + V^T via LDS transpose), N=1024, K=384
    gemm128<<<dim3(16, 32), blk, 0, stream>>>(ckvp, 384, WT + T_UKV, 384, 1024, 384, 3, nullptr, 0, k_attn, v_attnT, nullptr, nullptr);
    // 6) attention v4 (32x32 MFMA, in-register P, swizzled LDS)
    attn_v4<<<dim3(NSPLIT, 8, 16), blk, 0, stream>>>(q_attn, k_attn, v_attnT, po, ml_m, ml_l);
    // 7) combine
    attn_combine<<<dim3(1024), blk, 0, stream>>>(po, ml_m, ml_l, attn_o);
    // 8) output projection -> d_out (dual dtype)
    gemm128<<<dim3(8, 32), blk, 0, stream>>>(attn_o, DM, W_o, DM, DM, DM, 1, out_b, DM, nullptr, nullptr, flagp, out_f);
}

// Round 14
// 112.862 us; speedup vs baseline: 1.5735x; 1.5735x over previous
//
#include <hip/hip_runtime.h>
#include <hip/hip_bf16.h>

#define BATCH 2
#define SEQ 2048
#define DM 512
#define NH 8
#define DHD 64
#define QP 256
#define KVP 341
#define DQKPAD 96
#define MROWS 4096   // BATCH*SEQ

// bf16 arena element offsets (x, W_o, LN params only)
#define OFF_X     0
#define OFF_WO    2932224
#define OFF_QG    3194368
#define OFF_QB    3194624
#define OFF_KG    3194880
#define OFF_KB    3195221

// transposed-weight arena element offsets ([N][K])
#define T_DQ   0        // [256][512]
#define T_DKV  131072   // [384][512] (n>=341 zero)
#define T_KR   327680   // [64][512]
#define T_UQ   360448   // [512][256]
#define T_QR   491520   // [64][256]
#define T_UKV  507904   // [1024][384] (k>=341 zero)
#define T_TOT  901120

#define NW_X   2097152
#define NW_WO  262144
#define NW_PAR 1194

// prep work groups (8 elems each)
#define G_X   262144
#define G_WO  32768
#define G_PAR 150
#define G_WT  112640
#define G_TOT (G_X + G_WO + G_PAR + G_WT)

#define NSPLIT 4

typedef __bf16 bf16x8 __attribute__((ext_vector_type(8)));
typedef float f32x4 __attribute__((ext_vector_type(4)));
typedef __hip_bfloat16 bf16;
typedef unsigned short u16;

static __device__ __forceinline__ bf16x8 ld_bf8(const bf16* p) {
    return __builtin_bit_cast(bf16x8, *(const uint4*)p);
}

// async global->LDS, 16B per lane; LDS dest = wave-uniform base + lane*16
#define GL16(gp, lp) __builtin_amdgcn_global_load_lds( \
    (const __attribute__((address_space(1))) void*)(gp), \
    (__attribute__((address_space(3))) void*)(lp), 16, 0, 0)

// ---------- prep: dtype-flag + convert x/W_o/params + weight transposes (8-wide) ----------
__global__ __launch_bounds__(256) void prep(
    const void* px, const void* pwdq, const void* pwuq, const void* pwqr,
    const void* pwdkv, const void* pwukv, const void* pwkr, const void* pwo,
    const void* pqg, const void* pqb, const void* pkg, const void* pkb,
    u16* __restrict__ arena, u16* __restrict__ WT, int* __restrict__ flagp)
{
    __shared__ int cnt;
    if (threadIdx.x == 0) cnt = 0;
    __syncthreads();
    int bad = 0;
    const u16* xs = (const u16*)px;
    for (int i = threadIdx.x; i < 2048; i += 256) {
        u16 u = xs[i];
        int e = (u >> 7) & 0xFF;
        if (u != 0 && (e < 90 || e > 164)) bad++;
    }
    #pragma unroll
    for (int m2 = 1; m2 < 64; m2 <<= 1) bad += __shfl_xor(bad, m2);
    if ((threadIdx.x & 63) == 0) atomicAdd(&cnt, bad);
    __syncthreads();
    const int f = (cnt > 256) ? 1 : 0;   // 1 => inputs are fp32
    if (blockIdx.x == 0 && threadIdx.x == 0) *flagp = f;

    int gid = blockIdx.x * 256 + threadIdx.x;
    if (gid >= G_TOT) return;

    auto rdu = [&](const void* s, int i) -> u16 {
        if (f) return __builtin_bit_cast(u16, __float2bfloat16(((const float*)s)[i]));
        return ((const u16*)s)[i];
    };

    if (gid < G_X + G_WO) {
        const void* src = (gid < G_X) ? px : pwo;
        int base = (gid < G_X) ? OFF_X : OFF_WO;
        int i = (gid < G_X) ? gid : gid - G_X;
        u16 out[8];
        if (f) {
            const float* s = (const float*)src + i * 8;
            #pragma unroll
            for (int j = 0; j < 8; ++j) out[j] = __builtin_bit_cast(u16, __float2bfloat16(s[j]));
        } else {
            *(uint4*)out = ((const uint4*)src)[i];
        }
        *(uint4*)&arena[base + i * 8] = *(uint4*)out;
    } else if (gid < G_X + G_WO + G_PAR) {
        int i0 = (gid - G_X - G_WO) * 8;
        for (int j = 0; j < 8; ++j) {
            int i = i0 + j;
            if (i >= NW_PAR) break;
            if (i < 256)      arena[OFF_QG + i]         = rdu(pqg, i);
            else if (i < 512) arena[OFF_QB + (i - 256)] = rdu(pqb, i - 256);
            else if (i < 853) arena[OFF_KG + (i - 512)] = rdu(pkg, i - 512);
            else              arena[OFF_KB + (i - 853)] = rdu(pkb, i - 853);
        }
    } else {
        int loc = (gid - (G_X + G_WO + G_PAR)) * 8;   // 8 consecutive: same n, k0..k0+7
        const void* src; int n, k0, sN, klim, nok;
        if (loc < T_DKV)      { int l = loc;          n = l >> 9; k0 = l & 511; src = pwdq;  sN = 256;  klim = 512; nok = 1; }
        else if (loc < T_KR)  { int l = loc - T_DKV;  n = l >> 9; k0 = l & 511; src = pwdkv; sN = 341;  klim = 512; nok = (n < 341); }
        else if (loc < T_UQ)  { int l = loc - T_KR;   n = l >> 9; k0 = l & 511; src = pwkr;  sN = 64;   klim = 512; nok = 1; }
        else if (loc < T_QR)  { int l = loc - T_UQ;   n = l >> 8; k0 = l & 255; src = pwuq;  sN = 512;  klim = 256; nok = 1; }
        else if (loc < T_UKV) { int l = loc - T_QR;   n = l >> 8; k0 = l & 255; src = pwqr;  sN = 64;   klim = 256; nok = 1; }
        else                  { int l = loc - T_UKV;  n = l / 384; k0 = l % 384; src = pwukv; sN = 1024; klim = 341; nok = 1; }
        u16 out[8];
        #pragma unroll
        for (int j = 0; j < 8; ++j) {
            int k = k0 + j;
            out[j] = (nok && k < klim) ? rdu(src, k * sN + n) : (u16)0;
        }
        *(uint4*)&WT[loc] = *(uint4*)out;
    }
}

// ---------- rope epilogue: acc holds 64 rope cols for 128 rows; partner via shfl ----------
static __device__ __forceinline__ void rope_epi(
    f32x4 (&acc)[2][4], bf16* __restrict__ dst, int m0, int w, int g, int lr, int tid, bool scaleq)
{
    const float SCv = 0.11785113019775793f;   // 1/sqrt(72)
    #pragma unroll
    for (int mt = 0; mt < 2; ++mt)
    #pragma unroll
    for (int r = 0; r < 4; ++r) {
        int gm = m0 + w * 32 + mt * 16 + g * 4 + r;
        int s = gm & 2047, b = gm >> 11;
        float ang = (float)s * exp2f(-(float)(lr & 3) * 3.3219280948873623f);
        float sn, cs;
        sincosf(ang, &sn, &cs);
        #pragma unroll
        for (int nt = 0; nt < 4; ++nt) {
            float v = acc[mt][nt][r];
            float pt = __shfl_xor(v, 4);
            float o = (lr & 4) ? fmaf(pt, sn, v * cs) : fmaf(-pt, sn, v * cs);
            if (scaleq) o *= SCv;
            int h = (nt * 16 + lr) >> 3, j = lr & 7;
            dst[((size_t)(b * NH + h) * SEQ + s) * DQKPAD + 64 + j] = __float2bfloat16(o);
        }
    }
    // zero pads [72,96) for all 8 heads of these 128 rows
    for (int u = tid; u < 128 * 96; u += 256) {
        int rw = u / 96, rem = u - rw * 96;
        int h = rem / 12, c = rem - h * 12;
        int row = m0 + rw, b2 = row >> 11, s2 = row & 2047;
        *(unsigned int*)&dst[((size_t)(b2 * NH + h) * SEQ + s2) * DQKPAD + 72 + c * 2] = 0u;
    }
}

// ------- 128x64 bf16 MFMA GEMM body, BK=64, global_load_lds staging + XOR swizzle -------
// modes: 0 fp32->C0 (n0==640: kr-rope -> kv_k); 1 dual->C0/C0f;
// 3 KV-scatter (K direct, V via LDS transpose); 4 Q-scatter scaled (n0==512: q-rope).
static __device__ __forceinline__ void gemm_body(
    int bx, int by,
    const bf16* __restrict__ A, int lda,
    const bf16* __restrict__ BT, int ldb,
    int N, int Kpad, int mode,
    void* __restrict__ C0, int ldc,
    bf16* __restrict__ kv_k, bf16* __restrict__ kv_v,
    const int* __restrict__ flagp, float* __restrict__ C0f,
    bf16* LB)
{
    bf16* Al = LB;
    bf16* Bl = LB + 128 * 64;
    const int tid = threadIdx.x;
    const int m0 = by * 128, n0 = bx * 64;
    const int lane = tid & 63, w = tid >> 6;
    const int g = lane >> 4, lr = lane & 15;
    f32x4 acc[2][4] = {};
    const int r8 = lane >> 3;
    const int xr8 = ((lane & 7) ^ r8) * 8;     // pre-swizzled source column (elems)
    const int swx = (lr & 7) << 4;             // read-side XOR (bytes)

    for (int k0 = 0; k0 < Kpad; k0 += 64) {
        #pragma unroll
        for (int i = 0; i < 4; ++i)
            GL16(&A[(size_t)(m0 + w * 32 + i * 8 + r8) * lda + k0 + xr8],
                 (char*)Al + w * 4096 + i * 1024);
        #pragma unroll
        for (int i = 0; i < 2; ++i)
            GL16(&BT[(size_t)(n0 + w * 16 + i * 8 + r8) * ldb + k0 + xr8],
                 (char*)Bl + w * 2048 + i * 1024);
        __syncthreads();
        #pragma unroll
        for (int ks = 0; ks < 2; ++ks) {
            const int cs = (ks * 64 + g * 16) ^ swx;
            bf16x8 a0 = ld_bf8((const bf16*)((const char*)Al + (w * 32 + lr) * 128 + cs));
            bf16x8 a1 = ld_bf8((const bf16*)((const char*)Al + (w * 32 + 16 + lr) * 128 + cs));
            #pragma unroll
            for (int nt = 0; nt < 4; ++nt) {
                bf16x8 b = ld_bf8((const bf16*)((const char*)Bl + (nt * 16 + lr) * 128 + cs));
                acc[0][nt] = __builtin_amdgcn_mfma_f32_16x16x32_bf16(a0, b, acc[0][nt], 0, 0, 0);
                acc[1][nt] = __builtin_amdgcn_mfma_f32_16x16x32_bf16(a1, b, acc[1][nt], 0, 0, 0);
            }
        }
        __syncthreads();
    }

    if (mode == 0 && n0 == 640) {       // kr-rope block (unscaled) -> k_attn
        rope_epi(acc, kv_k, m0, w, g, lr, tid, false);
        return;
    }
    if (mode == 4 && n0 == DM) {        // qr-rope block (scaled) -> q_attn
        rope_epi(acc, (bf16*)C0, m0, w, g, lr, tid, true);
        return;
    }
    if (mode == 3 && n0 >= DM) {
        // V block: LDS transpose -> coalesced V^T rows
        const int h = (n0 - DM) >> 6;
        const int b = m0 >> 11, s0 = m0 & 2047;
        bf16* T = LB;   // [64][stride 136]
        #pragma unroll
        for (int mt = 0; mt < 2; ++mt)
        #pragma unroll
        for (int nt = 0; nt < 4; ++nt)
        #pragma unroll
        for (int r = 0; r < 4; ++r) {
            int dv = nt * 16 + lr;
            int sl = w * 32 + mt * 16 + g * 4 + r;
            T[dv * 136 + sl] = __float2bfloat16(acc[mt][nt][r]);
        }
        __syncthreads();
        const int row = tid >> 2, coff = (tid & 3) * 32;
        bf16* dst = &kv_v[((size_t)(b * NH + h) * DHD + row) * SEQ + s0 + coff];
        const bf16* srcp = &T[row * 136 + coff];
        #pragma unroll
        for (int q2 = 0; q2 < 4; ++q2)
            *(uint4*)(dst + q2 * 8) = *(const uint4*)(srcp + q2 * 8);
        return;
    }

    const float SCv = 0.11785113019775793f;
    const int f32o = (mode == 1 && flagp) ? *flagp : 0;
    #pragma unroll
    for (int mt = 0; mt < 2; ++mt)
    #pragma unroll
    for (int nt = 0; nt < 4; ++nt)
    #pragma unroll
    for (int r = 0; r < 4; ++r) {
        int gm = m0 + w * 32 + mt * 16 + g * 4 + r;
        int gn = n0 + nt * 16 + lr;
        float v = acc[mt][nt][r];
        if (mode == 0) {
            ((float*)C0)[(size_t)gm * ldc + gn] = v;
        } else if (mode == 1) {
            if (f32o) C0f[(size_t)gm * ldc + gn] = v;
            else ((bf16*)C0)[(size_t)gm * ldc + gn] = __float2bfloat16(v);
        } else if (mode == 4) {
            int b = gm >> 11, s = gm & 2047;
            int h = gn >> 6, dh = gn & 63;
            ((bf16*)C0)[((size_t)(b * NH + h) * SEQ + s) * DQKPAD + dh] = __float2bfloat16(v * SCv);
        } else { // mode 3 K block: direct scatter [bh][s][96]
            int b = gm >> 11, s = gm & 2047;
            int h = gn >> 6, dh = gn & 63;
            kv_k[((size_t)(b * NH + h) * SEQ + s) * DQKPAD + dh] = __float2bfloat16(v);
        }
    }
}

__global__ __launch_bounds__(256) void gemm128(
    const bf16* __restrict__ A, int lda,
    const bf16* __restrict__ BT, int ldb,
    int N, int Kpad, int mode,
    void* __restrict__ C0, int ldc,
    bf16* __restrict__ kv_k, bf16* __restrict__ kv_v,
    const int* __restrict__ flagp, float* __restrict__ C0f)
{
    __shared__ __align__(16) bf16 LB[128 * 64 + 64 * 64];   // Al 16KB | Bl 8KB
    gemm_body(blockIdx.x, blockIdx.y, A, lda, BT, ldb, N, Kpad, mode,
              C0, ldc, kv_k, kv_v, flagp, C0f, LB);
}

// ---- merged up-projections: blocks 0..8 = uq (N=576,K=256), 9..24 = ukv (N=1024,K=384) ----
__global__ __launch_bounds__(256) void gemm_dual(
    const bf16* __restrict__ A1, const bf16* __restrict__ BT1, void* __restrict__ C1,
    const bf16* __restrict__ A2, const bf16* __restrict__ BT2,
    bf16* __restrict__ kv_k, bf16* __restrict__ kv_v)
{
    __shared__ __align__(16) bf16 LB[128 * 64 + 64 * 64];
    if (blockIdx.x < 9) {
        gemm_body(blockIdx.x, blockIdx.y, A1, QP, BT1, QP, 576, QP, 4,
                  C1, 0, nullptr, nullptr, nullptr, nullptr, LB);
    } else {
        gemm_body(blockIdx.x - 9, blockIdx.y, A2, 384, BT2, 384, 1024, 384, 3,
                  nullptr, 0, kv_k, kv_v, nullptr, nullptr, LB);
    }
}

// ------- merged layernorms, one wave per row -------
__global__ __launch_bounds__(256) void ln_both(
    const float* __restrict__ y,
    const bf16* __restrict__ qg, const bf16* __restrict__ qb,
    const bf16* __restrict__ kg, const bf16* __restrict__ kb,
    bf16* __restrict__ cq, bf16* __restrict__ ckv_b, float* __restrict__ ckv_f,
    bf16* __restrict__ ckvp, const int* __restrict__ flagp)
{
    const int w = threadIdx.x >> 6, lane = threadIdx.x & 63;
    const int blk = blockIdx.x;
    if (blk < 1024) {
        const int row = blk * 4 + w;
        const float* yr = y + (size_t)row * 704;
        float s = 0.f, ss = 0.f;
        for (int i = lane; i < 256; i += 64) { float v = yr[i]; s += v; ss += v * v; }
        #pragma unroll
        for (int m = 1; m < 64; m <<= 1) { s += __shfl_xor(s, m); ss += __shfl_xor(ss, m); }
        float mean = s * (1.f / 256.f);
        float var = ss * (1.f / 256.f) - mean * mean;
        float rstd = rsqrtf(var + 1e-5f);
        for (int i = lane; i < 256; i += 64) {
            float v = (yr[i] - mean) * rstd * __bfloat162float(qg[i]) + __bfloat162float(qb[i]);
            cq[(size_t)row * 256 + i] = __float2bfloat16(v);
        }
    } else {
        const int row = (blk - 1024) * 4 + w;
        const float* yr = y + (size_t)row * 704 + 256;
        const int f32o = *flagp;
        float s = 0.f, ss = 0.f;
        for (int i = lane; i < KVP; i += 64) { float v = yr[i]; s += v; ss += v * v; }
        #pragma unroll
        for (int m = 1; m < 64; m <<= 1) { s += __shfl_xor(s, m); ss += __shfl_xor(ss, m); }
        float mean = s * (1.f / 341.f);
        float var = ss * (1.f / 341.f) - mean * mean;
        float rstd = rsqrtf(var + 1e-5f);
        for (int i = lane; i < KVP; i += 64) {
            float v = (yr[i] - mean) * rstd * __bfloat162float(kg[i]) + __bfloat162float(kb[i]);
            if (f32o) ckv_f[(size_t)row * KVP + i] = v;
            else ckv_b[(size_t)row * KVP + i] = __float2bfloat16(v);
            ckvp[(size_t)row * 384 + i] = __float2bfloat16(v);
        }
        for (int i = KVP + lane; i < 384; i += 64) ckvp[(size_t)row * 384 + i] = __float2bfloat16(0.f);
    }
}

// ---- causal flash attention: 4-way split-KV + qb-pairing + swapped QK^T
//      + defer-max + T14 async-STAGE (issue-early regs / write-late LDS) ----
__global__ __launch_bounds__(256) void attn_split3(
    const bf16* __restrict__ qa, const bf16* __restrict__ ka, const bf16* __restrict__ vat,
    bf16* __restrict__ po, float* __restrict__ mlm, float* __restrict__ mll)
{
    __shared__ __align__(16) bf16 Kl[64][104];
    __shared__ __align__(16) bf16 Vt[64][72];
    __shared__ __align__(16) bf16 Pl[4][16][72];
    const int sp = blockIdx.x, pr = blockIdx.y, bh = blockIdx.z;
    const int tid = threadIdx.x, w = tid >> 6, lane = tid & 63;
    const int g = lane >> 4, lr = lane & 15;
    const size_t base = (size_t)bh * SEQ;
    const float L2E = 1.4426950408889634f;
    const bf16* vb = vat + (size_t)bh * DHD * SEQ;

    uint4 kreg0, kreg1, kreg2, vreg0, vreg1;
    const int vd = tid >> 2, vko = (tid & 3) * 16;

    #define ISSUE_KV(j0)  do { \
        { int u0 = tid;       int row = u0 / 12, cc = (u0 % 12) * 8; kreg0 = *(const uint4*)&ka[(base + (j0) + row) * DQKPAD + cc]; } \
        { int u1 = tid + 256; int row = u1 / 12, cc = (u1 % 12) * 8; kreg1 = *(const uint4*)&ka[(base + (j0) + row) * DQKPAD + cc]; } \
        { int u2 = tid + 512; int row = u2 / 12, cc = (u2 % 12) * 8; kreg2 = *(const uint4*)&ka[(base + (j0) + row) * DQKPAD + cc]; } \
        const bf16* vsrc = &vb[(size_t)vd * SEQ + (j0) + vko]; \
        vreg0 = *(const uint4*)vsrc; vreg1 = *(const uint4*)(vsrc + 8); \
    } while (0)

    for (int half = 0; half < 2; ++half) {
        const int qb = half ? (31 - pr) : pr;
        const int qrow0 = qb * 64 + w * 16;
        const int myq = qrow0 + lr;

        bf16x8 qf[3];
        #pragma unroll
        for (int kc = 0; kc < 3; ++kc)
            qf[kc] = ld_bf8(&qa[(base + myq) * DQKPAD + kc * 32 + g * 8]);

        float m_p = -1e30f, l_p = 0.f;
        f32x4 acc_o[4] = {};
        const int ng = qb + 1;
        const int bs = (ng * sp) >> 2, be = (ng * (sp + 1)) >> 2;

        if (bs < be) ISSUE_KV(bs * 64);

        for (int gi = bs; gi < be; ++gi) {
            const int j0 = gi * 64;
            __syncthreads();
            { int u0 = tid;       int row = u0 / 12, cc = (u0 % 12) * 8; *(uint4*)&Kl[row][cc] = kreg0; }
            { int u1 = tid + 256; int row = u1 / 12, cc = (u1 % 12) * 8; *(uint4*)&Kl[row][cc] = kreg1; }
            { int u2 = tid + 512; int row = u2 / 12, cc = (u2 % 12) * 8; *(uint4*)&Kl[row][cc] = kreg2; }
            *(uint4*)&Vt[vd][vko]     = vreg0;
            *(uint4*)&Vt[vd][vko + 8] = vreg1;
            __syncthreads();
            if (gi + 1 < be) ISSUE_KV(j0 + 64);

            f32x4 accs[4] = {};
            #pragma unroll
            for (int kc = 0; kc < 3; ++kc) {
                #pragma unroll
                for (int nt = 0; nt < 4; ++nt) {
                    bf16x8 kf = ld_bf8(&Kl[nt * 16 + lr][kc * 32 + g * 8]);
                    accs[nt] = __builtin_amdgcn_mfma_f32_16x16x32_bf16(kf, qf[kc], accs[nt], 0, 0, 0);
                }
            }
            float s_[4][4];
            float mloc = -1e30f;
            if (j0 + 63 > qrow0) {
                #pragma unroll
                for (int nt = 0; nt < 4; ++nt)
                #pragma unroll
                for (int r = 0; r < 4; ++r) {
                    int key = j0 + nt * 16 + g * 4 + r;
                    float sv = accs[nt][r];
                    sv = (key <= myq) ? sv : -1e30f;
                    s_[nt][r] = sv;
                    mloc = fmaxf(mloc, sv);
                }
            } else {
                #pragma unroll
                for (int nt = 0; nt < 4; ++nt)
                #pragma unroll
                for (int r = 0; r < 4; ++r) {
                    float sv = accs[nt][r];
                    s_[nt][r] = sv;
                    mloc = fmaxf(mloc, sv);
                }
            }
            mloc = fmaxf(mloc, __shfl_xor(mloc, 16));
            mloc = fmaxf(mloc, __shfl_xor(mloc, 32));

            if (__all(mloc <= m_p + 8.f)) {
                float rs = 0.f;
                #pragma unroll
                for (int nt = 0; nt < 4; ++nt)
                #pragma unroll
                for (int r = 0; r < 4; ++r) {
                    float p = exp2f((s_[nt][r] - m_p) * L2E);
                    s_[nt][r] = p; rs += p;
                }
                rs += __shfl_xor(rs, 16);
                rs += __shfl_xor(rs, 32);
                l_p += rs;
            } else {
                float mn = fmaxf(m_p, mloc);
                float alpha = exp2f((m_p - mn) * L2E);
                m_p = mn;
                float rs = 0.f;
                #pragma unroll
                for (int nt = 0; nt < 4; ++nt)
                #pragma unroll
                for (int r = 0; r < 4; ++r) {
                    float p = exp2f((s_[nt][r] - mn) * L2E);
                    s_[nt][r] = p; rs += p;
                }
                rs += __shfl_xor(rs, 16);
                rs += __shfl_xor(rs, 32);
                l_p = l_p * alpha + rs;
                float ar[4];
                #pragma unroll
                for (int r = 0; r < 4; ++r) ar[r] = __shfl(alpha, g * 4 + r);
                #pragma unroll
                for (int nv = 0; nv < 4; ++nv)
                #pragma unroll
                for (int r = 0; r < 4; ++r) acc_o[nv][r] *= ar[r];
            }
            #pragma unroll
            for (int nt = 0; nt < 4; ++nt) {
                ushort4 pk;
                pk.x = __builtin_bit_cast(u16, __float2bfloat16(s_[nt][0]));
                pk.y = __builtin_bit_cast(u16, __float2bfloat16(s_[nt][1]));
                pk.z = __builtin_bit_cast(u16, __float2bfloat16(s_[nt][2]));
                pk.w = __builtin_bit_cast(u16, __float2bfloat16(s_[nt][3]));
                *(ushort4*)&Pl[w][lr][nt * 16 + g * 4] = pk;
            }
            bf16x8 pf0 = ld_bf8(&Pl[w][lr][g * 8]);
            bf16x8 pf1 = ld_bf8(&Pl[w][lr][32 + g * 8]);
            #pragma unroll
            for (int nv = 0; nv < 4; ++nv) {
                bf16x8 vf0 = ld_bf8(&Vt[nv * 16 + lr][g * 8]);
                acc_o[nv] = __builtin_amdgcn_mfma_f32_16x16x32_bf16(pf0, vf0, acc_o[nv], 0, 0, 0);
                bf16x8 vf1 = ld_bf8(&Vt[nv * 16 + lr][32 + g * 8]);
                acc_o[nv] = __builtin_amdgcn_mfma_f32_16x16x32_bf16(pf1, vf1, acc_o[nv], 0, 0, 0);
            }
        }

        const size_t pb = (size_t)(bh * NSPLIT + sp) * SEQ;
        #pragma unroll
        for (int r = 0; r < 4; ++r) {
            int qrow = qrow0 + g * 4 + r;
            #pragma unroll
            for (int nv = 0; nv < 4; ++nv)
                po[(pb + qrow) * DHD + nv * 16 + lr] = __float2bfloat16(acc_o[nv][r]);
        }
        if (lane < 16) {
            mlm[pb + qrow0 + lane] = m_p;
            mll[pb + qrow0 + lane] = l_p;
        }
    }
    #undef ISSUE_KV
}

// ---------------- combine split partials -> attn_o [b][s][h*64+d] ----------------
__global__ __launch_bounds__(256) void attn_combine(
    const bf16* __restrict__ po, const float* __restrict__ mlm, const float* __restrict__ mll,
    bf16* __restrict__ ao)
{
    int id = blockIdx.x * 256 + threadIdx.x;   // 16*2048*8 = 262144
    int bh = id >> 14;
    int rem = id & 16383;
    int q = rem >> 3, dc = (rem & 7) * 8;
    const float L2E = 1.4426950408889634f;
    size_t mlb = (size_t)bh * NSPLIT * SEQ + q;
    float ms[NSPLIT], ls[NSPLIT];
    #pragma unroll
    for (int s = 0; s < NSPLIT; ++s) { ms[s] = mlm[mlb + (size_t)s * SEQ]; ls[s] = mll[mlb + (size_t)s * SEQ]; }
    float M = -1e30f;
    #pragma unroll
    for (int s = 0; s < NSPLIT; ++s) M = fmaxf(M, ms[s]);
    float wsc[NSPLIT]; float L = 0.f;
    #pragma unroll
    for (int s = 0; s < NSPLIT; ++s) { wsc[s] = exp2f((ms[s] - M) * L2E); L += wsc[s] * ls[s]; }
    float o[8] = {};
    #pragma unroll
    for (int s = 0; s < NSPLIT; ++s) {
        if (ls[s] <= 0.f) continue;
        bf16x8 pv = ld_bf8(&po[((size_t)(bh * NSPLIT + s) * SEQ + q) * DHD + dc]);
        #pragma unroll
        for (int j = 0; j < 8; ++j) o[j] += wsc[s] * (float)pv[j];
    }
    float invL = 1.f / L;
    int b = bh >> 3, h = bh & 7;
    __bf16 tmp[8];
    #pragma unroll
    for (int j = 0; j < 8; ++j) tmp[j] = (__bf16)(o[j] * invL);
    *(uint4*)&ao[((size_t)(b * SEQ) + q) * DM + h * DHD + dc] = *(uint4*)tmp;
}

extern "C" void kernel_launch(void* const* d_in, const int* in_sizes, int n_in,
                              void* d_out, int out_size, void* d_ws, size_t ws_size,
                              hipStream_t stream) {
    char* ws = (char*)d_ws;
    bf16* AR      = (bf16*)(ws + 0);              // arena: x | W_o | params
    float* ml_m   = (float*)(ws + 0);             // alias x region (dead after x-gemm), 1MB
    float* ml_l   = (float*)(ws + 1048576);       // 1MB
    bf16* WT      = (bf16*)(ws + 6391296);        // transposed weights (1,802,240 B)
    int*  flagp   = (int*)(ws + 8193536);
    float* y      = (float*)(ws + 8194048);       // fused x-proj out [4096][704] fp32
    bf16* cq      = (bf16*)(ws + 19728384);       // [4096][256]
    bf16* ckvp    = (bf16*)(ws + 21825536);       // [4096][384]
    bf16* q_attn  = (bf16*)(ws + 26019840);
    bf16* k_attn  = (bf16*)(ws + 32311296);
    bf16* v_attnT = (bf16*)(ws + 38602752);
    bf16* attn_o  = (bf16*)(ws + 42797056);
    bf16* po      = (bf16*)(ws + 50331648);       // 4-split partials, 16,777,216 B

    const bf16* xb  = AR + OFF_X;
    const bf16* W_o = AR + OFF_WO;
    const bf16* qg  = AR + OFF_QG;
    const bf16* qb_ = AR + OFF_QB;
    const bf16* kg  = AR + OFF_KG;
    const bf16* kb  = AR + OFF_KB;

    bf16*  out_b = (bf16*)d_out;
    float* out_f = (float*)d_out;
    bf16*  ckv_b = out_b + (size_t)MROWS * DM;
    float* ckv_f = out_f + (size_t)MROWS * DM;

    dim3 blk(256);
    // 1) prep: flag + convert + weight transposes (8-wide)
    prep<<<dim3((G_TOT + 255) / 256), blk, 0, stream>>>(
        d_in[0], d_in[1], d_in[2], d_in[3], d_in[4], d_in[5],
        d_in[6], d_in[7], d_in[8], d_in[9], d_in[10], d_in[11],
        (u16*)AR, (u16*)WT, flagp);
    // 2) fused x-proj [dq|dkv|kr] N=704 (n0==640 block does kr-rope -> k_attn)
    gemm128<<<dim3(11, 32), blk, 0, stream>>>(xb, DM, WT + T_DQ, DM, 704, DM, 0, y, 704, k_attn, nullptr, nullptr, nullptr);
    // 3) merged layernorms
    ln_both<<<dim3(2048), blk, 0, stream>>>(y, qg, qb_, kg, kb, cq, ckv_b, ckv_f, ckvp, flagp);
    // 4+5) merged up-projections: uq (q-rope) + ukv (K/V^T scatter)
    gemm_dual<<<dim3(25, 32), blk, 0, stream>>>(cq, WT + T_UQ, q_attn, ckvp, WT + T_UKV, k_attn, v_attnT);
    // 6) attention (4-way split-KV, qb-paired, swapped-softmax, defer-max, T14)
    attn_split3<<<dim3(NSPLIT, 16, 16), blk, 0, stream>>>(q_attn, k_attn, v_attnT, po, ml_m, ml_l);
    // 7) combine
    attn_combine<<<dim3(1024), blk, 0, stream>>>(po, ml_m, ml_l, attn_o);
    // 8) output projection -> d_out (dual dtype)
    gemm128<<<dim3(8, 32), blk, 0, stream>>>(attn_o, DM, W_o, DM, DM, DM, 1, out_b, DM, nullptr, nullptr, flagp, out_f);
}

// Round 15
// 112.037 us; speedup vs baseline: 1.5851x; 1.0074x over previous
//
#include <hip/hip_runtime.h>
#include <hip/hip_bf16.h>

#define BATCH 2
#define SEQ 2048
#define DM 512
#define NH 8
#define DHD 64
#define QP 256
#define KVP 341
#define DQKPAD 96
#define MROWS 4096   // BATCH*SEQ

// bf16 arena element offsets (x, W_o, LN params only)
#define OFF_X     0
#define OFF_WO    2932224
#define OFF_QG    3194368
#define OFF_QB    3194624
#define OFF_KG    3194880
#define OFF_KB    3195221

// transposed-weight arena element offsets ([N][K])
#define T_DQ   0        // [256][512]
#define T_DKV  131072   // [384][512] (n>=341 zero)
#define T_KR   327680   // [64][512]
#define T_UQ   360448   // [512][256]
#define T_QR   491520   // [64][256]
#define T_UKV  507904   // [1024][384] (k>=341 zero)
#define T_TOT  901120

#define NW_X   2097152
#define NW_WO  262144
#define NW_PAR 1194

// prep work groups (8 elems each)
#define G_X   262144
#define G_WO  32768
#define G_PAR 150
#define G_WT  112640
#define G_TOT (G_X + G_WO + G_PAR + G_WT)

#define NSPLIT 4

typedef __bf16 bf16x8 __attribute__((ext_vector_type(8)));
typedef float f32x4 __attribute__((ext_vector_type(4)));
typedef __hip_bfloat16 bf16;
typedef unsigned short u16;

static __device__ __forceinline__ bf16x8 ld_bf8(const bf16* p) {
    return __builtin_bit_cast(bf16x8, *(const uint4*)p);
}

// async global->LDS, 16B per lane; LDS dest = wave-uniform base + lane*16
#define GL16(gp, lp) __builtin_amdgcn_global_load_lds( \
    (const __attribute__((address_space(1))) void*)(gp), \
    (__attribute__((address_space(3))) void*)(lp), 16, 0, 0)

// ---------- prep: dtype-flag + convert x/W_o/params + weight transposes (8-wide) ----------
__global__ __launch_bounds__(256) void prep(
    const void* px, const void* pwdq, const void* pwuq, const void* pwqr,
    const void* pwdkv, const void* pwukv, const void* pwkr, const void* pwo,
    const void* pqg, const void* pqb, const void* pkg, const void* pkb,
    u16* __restrict__ arena, u16* __restrict__ WT, int* __restrict__ flagp)
{
    __shared__ int cnt;
    if (threadIdx.x == 0) cnt = 0;
    __syncthreads();
    int bad = 0;
    const u16* xs = (const u16*)px;
    for (int i = threadIdx.x; i < 2048; i += 256) {
        u16 u = xs[i];
        int e = (u >> 7) & 0xFF;
        if (u != 0 && (e < 90 || e > 164)) bad++;
    }
    #pragma unroll
    for (int m2 = 1; m2 < 64; m2 <<= 1) bad += __shfl_xor(bad, m2);
    if ((threadIdx.x & 63) == 0) atomicAdd(&cnt, bad);
    __syncthreads();
    const int f = (cnt > 256) ? 1 : 0;   // 1 => inputs are fp32
    if (blockIdx.x == 0 && threadIdx.x == 0) *flagp = f;

    int gid = blockIdx.x * 256 + threadIdx.x;
    if (gid >= G_TOT) return;

    auto rdu = [&](const void* s, int i) -> u16 {
        if (f) return __builtin_bit_cast(u16, __float2bfloat16(((const float*)s)[i]));
        return ((const u16*)s)[i];
    };

    if (gid < G_X + G_WO) {
        const void* src = (gid < G_X) ? px : pwo;
        int base = (gid < G_X) ? OFF_X : OFF_WO;
        int i = (gid < G_X) ? gid : gid - G_X;
        u16 out[8];
        if (f) {
            const float* s = (const float*)src + i * 8;
            #pragma unroll
            for (int j = 0; j < 8; ++j) out[j] = __builtin_bit_cast(u16, __float2bfloat16(s[j]));
        } else {
            *(uint4*)out = ((const uint4*)src)[i];
        }
        *(uint4*)&arena[base + i * 8] = *(uint4*)out;
    } else if (gid < G_X + G_WO + G_PAR) {
        int i0 = (gid - G_X - G_WO) * 8;
        for (int j = 0; j < 8; ++j) {
            int i = i0 + j;
            if (i >= NW_PAR) break;
            if (i < 256)      arena[OFF_QG + i]         = rdu(pqg, i);
            else if (i < 512) arena[OFF_QB + (i - 256)] = rdu(pqb, i - 256);
            else if (i < 853) arena[OFF_KG + (i - 512)] = rdu(pkg, i - 512);
            else              arena[OFF_KB + (i - 853)] = rdu(pkb, i - 853);
        }
    } else {
        int loc = (gid - (G_X + G_WO + G_PAR)) * 8;   // 8 consecutive: same n, k0..k0+7
        const void* src; int n, k0, sN, klim, nok;
        if (loc < T_DKV)      { int l = loc;          n = l >> 9; k0 = l & 511; src = pwdq;  sN = 256;  klim = 512; nok = 1; }
        else if (loc < T_KR)  { int l = loc - T_DKV;  n = l >> 9; k0 = l & 511; src = pwdkv; sN = 341;  klim = 512; nok = (n < 341); }
        else if (loc < T_UQ)  { int l = loc - T_KR;   n = l >> 9; k0 = l & 511; src = pwkr;  sN = 64;   klim = 512; nok = 1; }
        else if (loc < T_QR)  { int l = loc - T_UQ;   n = l >> 8; k0 = l & 255; src = pwuq;  sN = 512;  klim = 256; nok = 1; }
        else if (loc < T_UKV) { int l = loc - T_QR;   n = l >> 8; k0 = l & 255; src = pwqr;  sN = 64;   klim = 256; nok = 1; }
        else                  { int l = loc - T_UKV;  n = l / 384; k0 = l % 384; src = pwukv; sN = 1024; klim = 341; nok = 1; }
        u16 out[8];
        #pragma unroll
        for (int j = 0; j < 8; ++j) {
            int k = k0 + j;
            out[j] = (nok && k < klim) ? rdu(src, k * sN + n) : (u16)0;
        }
        *(uint4*)&WT[loc] = *(uint4*)out;
    }
}

// ---------- rope epilogue: acc holds 64 rope cols for 128 rows; partner via shfl ----------
static __device__ __forceinline__ void rope_epi(
    f32x4 (&acc)[2][4], bf16* __restrict__ dst, int m0, int w, int g, int lr, int tid, bool scaleq)
{
    const float SCv = 0.11785113019775793f;   // 1/sqrt(72)
    #pragma unroll
    for (int mt = 0; mt < 2; ++mt)
    #pragma unroll
    for (int r = 0; r < 4; ++r) {
        int gm = m0 + w * 32 + mt * 16 + g * 4 + r;
        int s = gm & 2047, b = gm >> 11;
        float ang = (float)s * exp2f(-(float)(lr & 3) * 3.3219280948873623f);
        float sn, cs;
        sincosf(ang, &sn, &cs);
        #pragma unroll
        for (int nt = 0; nt < 4; ++nt) {
            float v = acc[mt][nt][r];
            float pt = __shfl_xor(v, 4);
            float o = (lr & 4) ? fmaf(pt, sn, v * cs) : fmaf(-pt, sn, v * cs);
            if (scaleq) o *= SCv;
            int h = (nt * 16 + lr) >> 3, j = lr & 7;
            dst[((size_t)(b * NH + h) * SEQ + s) * DQKPAD + 64 + j] = __float2bfloat16(o);
        }
    }
    // zero pads [72,96) for all 8 heads of these 128 rows
    for (int u = tid; u < 128 * 96; u += 256) {
        int rw = u / 96, rem = u - rw * 96;
        int h = rem / 12, c = rem - h * 12;
        int row = m0 + rw, b2 = row >> 11, s2 = row & 2047;
        *(unsigned int*)&dst[((size_t)(b2 * NH + h) * SEQ + s2) * DQKPAD + 72 + c * 2] = 0u;
    }
}

// ------- 128x64 bf16 MFMA GEMM body, BK=64, global_load_lds staging + XOR swizzle -------
static __device__ __forceinline__ void gemm_body(
    int bx, int by,
    const bf16* __restrict__ A, int lda,
    const bf16* __restrict__ BT, int ldb,
    int N, int Kpad, int mode,
    void* __restrict__ C0, int ldc,
    bf16* __restrict__ kv_k, bf16* __restrict__ kv_v,
    const int* __restrict__ flagp, float* __restrict__ C0f,
    bf16* LB)
{
    bf16* Al = LB;
    bf16* Bl = LB + 128 * 64;
    const int tid = threadIdx.x;
    const int m0 = by * 128, n0 = bx * 64;
    const int lane = tid & 63, w = tid >> 6;
    const int g = lane >> 4, lr = lane & 15;
    f32x4 acc[2][4] = {};
    const int r8 = lane >> 3;
    const int xr8 = ((lane & 7) ^ r8) * 8;     // pre-swizzled source column (elems)
    const int swx = (lr & 7) << 4;             // read-side XOR (bytes)

    for (int k0 = 0; k0 < Kpad; k0 += 64) {
        #pragma unroll
        for (int i = 0; i < 4; ++i)
            GL16(&A[(size_t)(m0 + w * 32 + i * 8 + r8) * lda + k0 + xr8],
                 (char*)Al + w * 4096 + i * 1024);
        #pragma unroll
        for (int i = 0; i < 2; ++i)
            GL16(&BT[(size_t)(n0 + w * 16 + i * 8 + r8) * ldb + k0 + xr8],
                 (char*)Bl + w * 2048 + i * 1024);
        __syncthreads();
        #pragma unroll
        for (int ks = 0; ks < 2; ++ks) {
            const int cs = (ks * 64 + g * 16) ^ swx;
            bf16x8 a0 = ld_bf8((const bf16*)((const char*)Al + (w * 32 + lr) * 128 + cs));
            bf16x8 a1 = ld_bf8((const bf16*)((const char*)Al + (w * 32 + 16 + lr) * 128 + cs));
            #pragma unroll
            for (int nt = 0; nt < 4; ++nt) {
                bf16x8 b = ld_bf8((const bf16*)((const char*)Bl + (nt * 16 + lr) * 128 + cs));
                acc[0][nt] = __builtin_amdgcn_mfma_f32_16x16x32_bf16(a0, b, acc[0][nt], 0, 0, 0);
                acc[1][nt] = __builtin_amdgcn_mfma_f32_16x16x32_bf16(a1, b, acc[1][nt], 0, 0, 0);
            }
        }
        __syncthreads();
    }

    if (mode == 0 && n0 == 640) {       // kr-rope block (unscaled) -> k_attn
        rope_epi(acc, kv_k, m0, w, g, lr, tid, false);
        return;
    }
    if (mode == 4 && n0 == DM) {        // qr-rope block (scaled) -> q_attn
        rope_epi(acc, (bf16*)C0, m0, w, g, lr, tid, true);
        return;
    }
    if (mode == 3 && n0 >= DM) {
        // V block: LDS transpose -> coalesced V^T rows
        const int h = (n0 - DM) >> 6;
        const int b = m0 >> 11, s0 = m0 & 2047;
        bf16* T = LB;   // [64][stride 136]
        #pragma unroll
        for (int mt = 0; mt < 2; ++mt)
        #pragma unroll
        for (int nt = 0; nt < 4; ++nt)
        #pragma unroll
        for (int r = 0; r < 4; ++r) {
            int dv = nt * 16 + lr;
            int sl = w * 32 + mt * 16 + g * 4 + r;
            T[dv * 136 + sl] = __float2bfloat16(acc[mt][nt][r]);
        }
        __syncthreads();
        const int row = tid >> 2, coff = (tid & 3) * 32;
        bf16* dst = &kv_v[((size_t)(b * NH + h) * DHD + row) * SEQ + s0 + coff];
        const bf16* srcp = &T[row * 136 + coff];
        #pragma unroll
        for (int q2 = 0; q2 < 4; ++q2)
            *(uint4*)(dst + q2 * 8) = *(const uint4*)(srcp + q2 * 8);
        return;
    }

    const float SCv = 0.11785113019775793f;
    const int f32o = (mode == 1 && flagp) ? *flagp : 0;
    #pragma unroll
    for (int mt = 0; mt < 2; ++mt)
    #pragma unroll
    for (int nt = 0; nt < 4; ++nt)
    #pragma unroll
    for (int r = 0; r < 4; ++r) {
        int gm = m0 + w * 32 + mt * 16 + g * 4 + r;
        int gn = n0 + nt * 16 + lr;
        float v = acc[mt][nt][r];
        if (mode == 0) {
            ((float*)C0)[(size_t)gm * ldc + gn] = v;
        } else if (mode == 1) {
            if (f32o) C0f[(size_t)gm * ldc + gn] = v;
            else ((bf16*)C0)[(size_t)gm * ldc + gn] = __float2bfloat16(v);
        } else if (mode == 4) {
            int b = gm >> 11, s = gm & 2047;
            int h = gn >> 6, dh = gn & 63;
            ((bf16*)C0)[((size_t)(b * NH + h) * SEQ + s) * DQKPAD + dh] = __float2bfloat16(v * SCv);
        } else { // mode 3 K block: direct scatter [bh][s][96]
            int b = gm >> 11, s = gm & 2047;
            int h = gn >> 6, dh = gn & 63;
            kv_k[((size_t)(b * NH + h) * SEQ + s) * DQKPAD + dh] = __float2bfloat16(v);
        }
    }
}

__global__ __launch_bounds__(256) void gemm128(
    const bf16* __restrict__ A, int lda,
    const bf16* __restrict__ BT, int ldb,
    int N, int Kpad, int mode,
    void* __restrict__ C0, int ldc,
    bf16* __restrict__ kv_k, bf16* __restrict__ kv_v,
    const int* __restrict__ flagp, float* __restrict__ C0f)
{
    __shared__ __align__(16) bf16 LB[128 * 64 + 64 * 64];   // Al 16KB | Bl 8KB
    gemm_body(blockIdx.x, blockIdx.y, A, lda, BT, ldb, N, Kpad, mode,
              C0, ldc, kv_k, kv_v, flagp, C0f, LB);
}

// ---- merged up-projections: blocks 0..8 = uq (N=576,K=256), 9..24 = ukv (N=1024,K=384) ----
__global__ __launch_bounds__(256) void gemm_dual(
    const bf16* __restrict__ A1, const bf16* __restrict__ BT1, void* __restrict__ C1,
    const bf16* __restrict__ A2, const bf16* __restrict__ BT2,
    bf16* __restrict__ kv_k, bf16* __restrict__ kv_v)
{
    __shared__ __align__(16) bf16 LB[128 * 64 + 64 * 64];
    if (blockIdx.x < 9) {
        gemm_body(blockIdx.x, blockIdx.y, A1, QP, BT1, QP, 576, QP, 4,
                  C1, 0, nullptr, nullptr, nullptr, nullptr, LB);
    } else {
        gemm_body(blockIdx.x - 9, blockIdx.y, A2, 384, BT2, 384, 1024, 384, 3,
                  nullptr, 0, kv_k, kv_v, nullptr, nullptr, LB);
    }
}

// ------- merged layernorms, one wave per row -------
__global__ __launch_bounds__(256) void ln_both(
    const float* __restrict__ y,
    const bf16* __restrict__ qg, const bf16* __restrict__ qb,
    const bf16* __restrict__ kg, const bf16* __restrict__ kb,
    bf16* __restrict__ cq, bf16* __restrict__ ckv_b, float* __restrict__ ckv_f,
    bf16* __restrict__ ckvp, const int* __restrict__ flagp)
{
    const int w = threadIdx.x >> 6, lane = threadIdx.x & 63;
    const int blk = blockIdx.x;
    if (blk < 1024) {
        const int row = blk * 4 + w;
        const float* yr = y + (size_t)row * 704;
        float s = 0.f, ss = 0.f;
        for (int i = lane; i < 256; i += 64) { float v = yr[i]; s += v; ss += v * v; }
        #pragma unroll
        for (int m = 1; m < 64; m <<= 1) { s += __shfl_xor(s, m); ss += __shfl_xor(ss, m); }
        float mean = s * (1.f / 256.f);
        float var = ss * (1.f / 256.f) - mean * mean;
        float rstd = rsqrtf(var + 1e-5f);
        for (int i = lane; i < 256; i += 64) {
            float v = (yr[i] - mean) * rstd * __bfloat162float(qg[i]) + __bfloat162float(qb[i]);
            cq[(size_t)row * 256 + i] = __float2bfloat16(v);
        }
    } else {
        const int row = (blk - 1024) * 4 + w;
        const float* yr = y + (size_t)row * 704 + 256;
        const int f32o = *flagp;
        float s = 0.f, ss = 0.f;
        for (int i = lane; i < KVP; i += 64) { float v = yr[i]; s += v; ss += v * v; }
        #pragma unroll
        for (int m = 1; m < 64; m <<= 1) { s += __shfl_xor(s, m); ss += __shfl_xor(ss, m); }
        float mean = s * (1.f / 341.f);
        float var = ss * (1.f / 341.f) - mean * mean;
        float rstd = rsqrtf(var + 1e-5f);
        for (int i = lane; i < KVP; i += 64) {
            float v = (yr[i] - mean) * rstd * __bfloat162float(kg[i]) + __bfloat162float(kb[i]);
            if (f32o) ckv_f[(size_t)row * KVP + i] = v;
            else ckv_b[(size_t)row * KVP + i] = __float2bfloat16(v);
            ckvp[(size_t)row * 384 + i] = __float2bfloat16(v);
        }
        for (int i = KVP + lane; i < 384; i += 64) ckvp[(size_t)row * 384 + i] = __float2bfloat16(0.f);
    }
}

// ---- causal flash attention: 4-way split-KV + qb-pairing + swapped QK^T
//      + defer-max + T14 async-STAGE + T2 Kl-swizzle + T5 setprio ----
__global__ __launch_bounds__(256) void attn_split3(
    const bf16* __restrict__ qa, const bf16* __restrict__ ka, const bf16* __restrict__ vat,
    bf16* __restrict__ po, float* __restrict__ mlm, float* __restrict__ mll)
{
    __shared__ __align__(16) bf16 Kl[64][128];   // 16 swizzled 8-elem slots (12 used)
    __shared__ __align__(16) bf16 Vt[64][72];
    __shared__ __align__(16) bf16 Pl[4][16][72];
    const int sp = blockIdx.x, pr = blockIdx.y, bh = blockIdx.z;
    const int tid = threadIdx.x, w = tid >> 6, lane = tid & 63;
    const int g = lane >> 4, lr = lane & 15;
    const size_t base = (size_t)bh * SEQ;
    const float L2E = 1.4426950408889634f;
    const bf16* vb = vat + (size_t)bh * DHD * SEQ;

    uint4 kreg0, kreg1, kreg2, vreg0, vreg1;
    const int vd = tid >> 2, vko = (tid & 3) * 16;
    // K staging decomposition (row, slot) per chunk, precomputed with swizzle
    const int kr0 = tid / 12,          ks0 = tid % 12;
    const int kr1 = (tid + 256) / 12,  ks1 = (tid + 256) % 12;
    const int kr2 = (tid + 512) / 12,  ks2 = (tid + 512) % 12;
    const int kx0 = (ks0 ^ (kr0 & 15)) * 8;
    const int kx1 = (ks1 ^ (kr1 & 15)) * 8;
    const int kx2 = (ks2 ^ (kr2 & 15)) * 8;

    #define ISSUE_KV(j0)  do { \
        kreg0 = *(const uint4*)&ka[(base + (j0) + kr0) * DQKPAD + ks0 * 8]; \
        kreg1 = *(const uint4*)&ka[(base + (j0) + kr1) * DQKPAD + ks1 * 8]; \
        kreg2 = *(const uint4*)&ka[(base + (j0) + kr2) * DQKPAD + ks2 * 8]; \
        const bf16* vsrc = &vb[(size_t)vd * SEQ + (j0) + vko]; \
        vreg0 = *(const uint4*)vsrc; vreg1 = *(const uint4*)(vsrc + 8); \
    } while (0)

    for (int half = 0; half < 2; ++half) {
        const int qb = half ? (31 - pr) : pr;
        const int qrow0 = qb * 64 + w * 16;
        const int myq = qrow0 + lr;

        bf16x8 qf[3];
        #pragma unroll
        for (int kc = 0; kc < 3; ++kc)
            qf[kc] = ld_bf8(&qa[(base + myq) * DQKPAD + kc * 32 + g * 8]);

        float m_p = -1e30f, l_p = 0.f;
        f32x4 acc_o[4] = {};
        const int ng = qb + 1;
        const int bs = (ng * sp) >> 2, be = (ng * (sp + 1)) >> 2;

        if (bs < be) ISSUE_KV(bs * 64);

        for (int gi = bs; gi < be; ++gi) {
            const int j0 = gi * 64;
            __syncthreads();
            *(uint4*)&Kl[kr0][kx0] = kreg0;
            *(uint4*)&Kl[kr1][kx1] = kreg1;
            *(uint4*)&Kl[kr2][kx2] = kreg2;
            *(uint4*)&Vt[vd][vko]     = vreg0;
            *(uint4*)&Vt[vd][vko + 8] = vreg1;
            __syncthreads();
            if (gi + 1 < be) ISSUE_KV(j0 + 64);

            f32x4 accs[4] = {};
            __builtin_amdgcn_s_setprio(1);
            #pragma unroll
            for (int kc = 0; kc < 3; ++kc) {
                #pragma unroll
                for (int nt = 0; nt < 4; ++nt) {
                    // row = nt*16+lr, row&15 = lr; slot = kc*4+g -> swizzled ^lr
                    bf16x8 kf = ld_bf8(&Kl[nt * 16 + lr][((kc * 4 + g) ^ lr) * 8]);
                    accs[nt] = __builtin_amdgcn_mfma_f32_16x16x32_bf16(kf, qf[kc], accs[nt], 0, 0, 0);
                }
            }
            __builtin_amdgcn_s_setprio(0);
            float s_[4][4];
            float mloc = -1e30f;
            if (j0 + 63 > qrow0) {
                #pragma unroll
                for (int nt = 0; nt < 4; ++nt)
                #pragma unroll
                for (int r = 0; r < 4; ++r) {
                    int key = j0 + nt * 16 + g * 4 + r;
                    float sv = accs[nt][r];
                    sv = (key <= myq) ? sv : -1e30f;
                    s_[nt][r] = sv;
                    mloc = fmaxf(mloc, sv);
                }
            } else {
                #pragma unroll
                for (int nt = 0; nt < 4; ++nt)
                #pragma unroll
                for (int r = 0; r < 4; ++r) {
                    float sv = accs[nt][r];
                    s_[nt][r] = sv;
                    mloc = fmaxf(mloc, sv);
                }
            }
            mloc = fmaxf(mloc, __shfl_xor(mloc, 16));
            mloc = fmaxf(mloc, __shfl_xor(mloc, 32));

            if (__all(mloc <= m_p + 8.f)) {
                float rs = 0.f;
                #pragma unroll
                for (int nt = 0; nt < 4; ++nt)
                #pragma unroll
                for (int r = 0; r < 4; ++r) {
                    float p = exp2f((s_[nt][r] - m_p) * L2E);
                    s_[nt][r] = p; rs += p;
                }
                rs += __shfl_xor(rs, 16);
                rs += __shfl_xor(rs, 32);
                l_p += rs;
            } else {
                float mn = fmaxf(m_p, mloc);
                float alpha = exp2f((m_p - mn) * L2E);
                m_p = mn;
                float rs = 0.f;
                #pragma unroll
                for (int nt = 0; nt < 4; ++nt)
                #pragma unroll
                for (int r = 0; r < 4; ++r) {
                    float p = exp2f((s_[nt][r] - mn) * L2E);
                    s_[nt][r] = p; rs += p;
                }
                rs += __shfl_xor(rs, 16);
                rs += __shfl_xor(rs, 32);
                l_p = l_p * alpha + rs;
                float ar[4];
                #pragma unroll
                for (int r = 0; r < 4; ++r) ar[r] = __shfl(alpha, g * 4 + r);
                #pragma unroll
                for (int nv = 0; nv < 4; ++nv)
                #pragma unroll
                for (int r = 0; r < 4; ++r) acc_o[nv][r] *= ar[r];
            }
            #pragma unroll
            for (int nt = 0; nt < 4; ++nt) {
                ushort4 pk;
                pk.x = __builtin_bit_cast(u16, __float2bfloat16(s_[nt][0]));
                pk.y = __builtin_bit_cast(u16, __float2bfloat16(s_[nt][1]));
                pk.z = __builtin_bit_cast(u16, __float2bfloat16(s_[nt][2]));
                pk.w = __builtin_bit_cast(u16, __float2bfloat16(s_[nt][3]));
                *(ushort4*)&Pl[w][lr][nt * 16 + g * 4] = pk;
            }
            bf16x8 pf0 = ld_bf8(&Pl[w][lr][g * 8]);
            bf16x8 pf1 = ld_bf8(&Pl[w][lr][32 + g * 8]);
            __builtin_amdgcn_s_setprio(1);
            #pragma unroll
            for (int nv = 0; nv < 4; ++nv) {
                bf16x8 vf0 = ld_bf8(&Vt[nv * 16 + lr][g * 8]);
                acc_o[nv] = __builtin_amdgcn_mfma_f32_16x16x32_bf16(pf0, vf0, acc_o[nv], 0, 0, 0);
                bf16x8 vf1 = ld_bf8(&Vt[nv * 16 + lr][32 + g * 8]);
                acc_o[nv] = __builtin_amdgcn_mfma_f32_16x16x32_bf16(pf1, vf1, acc_o[nv], 0, 0, 0);
            }
            __builtin_amdgcn_s_setprio(0);
        }

        const size_t pb = (size_t)(bh * NSPLIT + sp) * SEQ;
        #pragma unroll
        for (int r = 0; r < 4; ++r) {
            int qrow = qrow0 + g * 4 + r;
            #pragma unroll
            for (int nv = 0; nv < 4; ++nv)
                po[(pb + qrow) * DHD + nv * 16 + lr] = __float2bfloat16(acc_o[nv][r]);
        }
        if (lane < 16) {
            mlm[pb + qrow0 + lane] = m_p;
            mll[pb + qrow0 + lane] = l_p;
        }
    }
    #undef ISSUE_KV
}

// ---------------- combine split partials -> attn_o [b][s][h*64+d] ----------------
__global__ __launch_bounds__(256) void attn_combine(
    const bf16* __restrict__ po, const float* __restrict__ mlm, const float* __restrict__ mll,
    bf16* __restrict__ ao)
{
    int id = blockIdx.x * 256 + threadIdx.x;   // 16*2048*8 = 262144
    int bh = id >> 14;
    int rem = id & 16383;
    int q = rem >> 3, dc = (rem & 7) * 8;
    const float L2E = 1.4426950408889634f;
    size_t mlb = (size_t)bh * NSPLIT * SEQ + q;
    float ms[NSPLIT], ls[NSPLIT];
    #pragma unroll
    for (int s = 0; s < NSPLIT; ++s) { ms[s] = mlm[mlb + (size_t)s * SEQ]; ls[s] = mll[mlb + (size_t)s * SEQ]; }
    float M = -1e30f;
    #pragma unroll
    for (int s = 0; s < NSPLIT; ++s) M = fmaxf(M, ms[s]);
    float wsc[NSPLIT]; float L = 0.f;
    #pragma unroll
    for (int s = 0; s < NSPLIT; ++s) { wsc[s] = exp2f((ms[s] - M) * L2E); L += wsc[s] * ls[s]; }
    float o[8] = {};
    #pragma unroll
    for (int s = 0; s < NSPLIT; ++s) {
        if (ls[s] <= 0.f) continue;
        bf16x8 pv = ld_bf8(&po[((size_t)(bh * NSPLIT + s) * SEQ + q) * DHD + dc]);
        #pragma unroll
        for (int j = 0; j < 8; ++j) o[j] += wsc[s] * (float)pv[j];
    }
    float invL = 1.f / L;
    int b = bh >> 3, h = bh & 7;
    __bf16 tmp[8];
    #pragma unroll
    for (int j = 0; j < 8; ++j) tmp[j] = (__bf16)(o[j] * invL);
    *(uint4*)&ao[((size_t)(b * SEQ) + q) * DM + h * DHD + dc] = *(uint4*)tmp;
}

extern "C" void kernel_launch(void* const* d_in, const int* in_sizes, int n_in,
                              void* d_out, int out_size, void* d_ws, size_t ws_size,
                              hipStream_t stream) {
    char* ws = (char*)d_ws;
    bf16* AR      = (bf16*)(ws + 0);              // arena: x | W_o | params
    float* ml_m   = (float*)(ws + 0);             // alias x region (dead after x-gemm), 1MB
    float* ml_l   = (float*)(ws + 1048576);       // 1MB
    bf16* WT      = (bf16*)(ws + 6391296);        // transposed weights (1,802,240 B)
    int*  flagp   = (int*)(ws + 8193536);
    float* y      = (float*)(ws + 8194048);       // fused x-proj out [4096][704] fp32
    bf16* cq      = (bf16*)(ws + 19728384);       // [4096][256]
    bf16* ckvp    = (bf16*)(ws + 21825536);       // [4096][384]
    bf16* q_attn  = (bf16*)(ws + 26019840);
    bf16* k_attn  = (bf16*)(ws + 32311296);
    bf16* v_attnT = (bf16*)(ws + 38602752);
    bf16* attn_o  = (bf16*)(ws + 42797056);
    bf16* po      = (bf16*)(ws + 50331648);       // 4-split partials, 16,777,216 B

    const bf16* xb  = AR + OFF_X;
    const bf16* W_o = AR + OFF_WO;
    const bf16* qg  = AR + OFF_QG;
    const bf16* qb_ = AR + OFF_QB;
    const bf16* kg  = AR + OFF_KG;
    const bf16* kb  = AR + OFF_KB;

    bf16*  out_b = (bf16*)d_out;
    float* out_f = (float*)d_out;
    bf16*  ckv_b = out_b + (size_t)MROWS * DM;
    float* ckv_f = out_f + (size_t)MROWS * DM;

    dim3 blk(256);
    // 1) prep: flag + convert + weight transposes (8-wide)
    prep<<<dim3((G_TOT + 255) / 256), blk, 0, stream>>>(
        d_in[0], d_in[1], d_in[2], d_in[3], d_in[4], d_in[5],
        d_in[6], d_in[7], d_in[8], d_in[9], d_in[10], d_in[11],
        (u16*)AR, (u16*)WT, flagp);
    // 2) fused x-proj [dq|dkv|kr] N=704 (n0==640 block does kr-rope -> k_attn)
    gemm128<<<dim3(11, 32), blk, 0, stream>>>(xb, DM, WT + T_DQ, DM, 704, DM, 0, y, 704, k_attn, nullptr, nullptr, nullptr);
    // 3) merged layernorms
    ln_both<<<dim3(2048), blk, 0, stream>>>(y, qg, qb_, kg, kb, cq, ckv_b, ckv_f, ckvp, flagp);
    // 4+5) merged up-projections: uq (q-rope) + ukv (K/V^T scatter)
    gemm_dual<<<dim3(25, 32), blk, 0, stream>>>(cq, WT + T_UQ, q_attn, ckvp, WT + T_UKV, k_attn, v_attnT);
    // 6) attention (4-way split-KV, qb-paired, swapped-softmax, defer-max, T14, T2, T5)
    attn_split3<<<dim3(NSPLIT, 16, 16), blk, 0, stream>>>(q_attn, k_attn, v_attnT, po, ml_m, ml_l);
    // 7) combine
    attn_combine<<<dim3(1024), blk, 0, stream>>>(po, ml_m, ml_l, attn_o);
    // 8) output projection -> d_out (dual dtype)
    gemm128<<<dim3(8, 32), blk, 0, stream>>>(attn_o, DM, W_o, DM, DM, DM, 1, out_b, DM, nullptr, nullptr, flagp, out_f);
}

// Round 16
// 110.995 us; speedup vs baseline: 1.6000x; 1.0094x over previous
//
#include <hip/hip_runtime.h>
#include <hip/hip_bf16.h>

#define BATCH 2
#define SEQ 2048
#define DM 512
#define NH 8
#define DHD 64
#define QP 256
#define KVP 341
#define DQKPAD 96
#define MROWS 4096   // BATCH*SEQ

// bf16 arena element offsets (x, W_o, LN params only)
#define OFF_X     0
#define OFF_WO    2932224
#define OFF_QG    3194368
#define OFF_QB    3194624
#define OFF_KG    3194880
#define OFF_KB    3195221

// transposed-weight arena element offsets ([N][K])
#define T_DQ   0        // [256][512]
#define T_DKV  131072   // [384][512] (n>=341 zero)
#define T_KR   327680   // [64][512]
#define T_UQ   360448   // [512][256]
#define T_QR   491520   // [64][256]
#define T_UKV  507904   // [1024][384] (k>=341 zero)
#define T_TOT  901120

#define NW_X   2097152
#define NW_WO  262144
#define NW_PAR 1194

// prep work groups (8 elems each)
#define G_X   262144
#define G_WO  32768
#define G_PAR 150
#define G_WT  112640
#define G_TOT (G_X + G_WO + G_PAR + G_WT)

#define NSPLIT 4

typedef __bf16 bf16x8 __attribute__((ext_vector_type(8)));
typedef float f32x4 __attribute__((ext_vector_type(4)));
typedef __hip_bfloat16 bf16;
typedef unsigned short u16;

static __device__ __forceinline__ bf16x8 ld_bf8(const bf16* p) {
    return __builtin_bit_cast(bf16x8, *(const uint4*)p);
}

// async global->LDS, 16B per lane; LDS dest = wave-uniform base + lane*16
#define GL16(gp, lp) __builtin_amdgcn_global_load_lds( \
    (const __attribute__((address_space(1))) void*)(gp), \
    (__attribute__((address_space(3))) void*)(lp), 16, 0, 0)

// ---------- prep: dtype-flag + convert x/W_o/params + weight transposes (8-wide) ----------
__global__ __launch_bounds__(256) void prep(
    const void* px, const void* pwdq, const void* pwuq, const void* pwqr,
    const void* pwdkv, const void* pwukv, const void* pwkr, const void* pwo,
    const void* pqg, const void* pqb, const void* pkg, const void* pkb,
    u16* __restrict__ arena, u16* __restrict__ WT, int* __restrict__ flagp)
{
    __shared__ int cnt;
    if (threadIdx.x == 0) cnt = 0;
    __syncthreads();
    int bad = 0;
    const u16* xs = (const u16*)px;
    for (int i = threadIdx.x; i < 2048; i += 256) {
        u16 u = xs[i];
        int e = (u >> 7) & 0xFF;
        if (u != 0 && (e < 90 || e > 164)) bad++;
    }
    #pragma unroll
    for (int m2 = 1; m2 < 64; m2 <<= 1) bad += __shfl_xor(bad, m2);
    if ((threadIdx.x & 63) == 0) atomicAdd(&cnt, bad);
    __syncthreads();
    const int f = (cnt > 256) ? 1 : 0;   // 1 => inputs are fp32
    if (blockIdx.x == 0 && threadIdx.x == 0) *flagp = f;

    int gid = blockIdx.x * 256 + threadIdx.x;
    if (gid >= G_TOT) return;

    auto rdu = [&](const void* s, int i) -> u16 {
        if (f) return __builtin_bit_cast(u16, __float2bfloat16(((const float*)s)[i]));
        return ((const u16*)s)[i];
    };

    if (gid < G_X + G_WO) {
        const void* src = (gid < G_X) ? px : pwo;
        int base = (gid < G_X) ? OFF_X : OFF_WO;
        int i = (gid < G_X) ? gid : gid - G_X;
        u16 out[8];
        if (f) {
            const float* s = (const float*)src + i * 8;
            #pragma unroll
            for (int j = 0; j < 8; ++j) out[j] = __builtin_bit_cast(u16, __float2bfloat16(s[j]));
        } else {
            *(uint4*)out = ((const uint4*)src)[i];
        }
        *(uint4*)&arena[base + i * 8] = *(uint4*)out;
    } else if (gid < G_X + G_WO + G_PAR) {
        int i0 = (gid - G_X - G_WO) * 8;
        for (int j = 0; j < 8; ++j) {
            int i = i0 + j;
            if (i >= NW_PAR) break;
            if (i < 256)      arena[OFF_QG + i]         = rdu(pqg, i);
            else if (i < 512) arena[OFF_QB + (i - 256)] = rdu(pqb, i - 256);
            else if (i < 853) arena[OFF_KG + (i - 512)] = rdu(pkg, i - 512);
            else              arena[OFF_KB + (i - 853)] = rdu(pkb, i - 853);
        }
    } else {
        int loc = (gid - (G_X + G_WO + G_PAR)) * 8;   // 8 consecutive: same n, k0..k0+7
        const void* src; int n, k0, sN, klim, nok;
        if (loc < T_DKV)      { int l = loc;          n = l >> 9; k0 = l & 511; src = pwdq;  sN = 256;  klim = 512; nok = 1; }
        else if (loc < T_KR)  { int l = loc - T_DKV;  n = l >> 9; k0 = l & 511; src = pwdkv; sN = 341;  klim = 512; nok = (n < 341); }
        else if (loc < T_UQ)  { int l = loc - T_KR;   n = l >> 9; k0 = l & 511; src = pwkr;  sN = 64;   klim = 512; nok = 1; }
        else if (loc < T_QR)  { int l = loc - T_UQ;   n = l >> 8; k0 = l & 255; src = pwuq;  sN = 512;  klim = 256; nok = 1; }
        else if (loc < T_UKV) { int l = loc - T_QR;   n = l >> 8; k0 = l & 255; src = pwqr;  sN = 64;   klim = 256; nok = 1; }
        else                  { int l = loc - T_UKV;  n = l / 384; k0 = l % 384; src = pwukv; sN = 1024; klim = 341; nok = 1; }
        u16 out[8];
        #pragma unroll
        for (int j = 0; j < 8; ++j) {
            int k = k0 + j;
            out[j] = (nok && k < klim) ? rdu(src, k * sN + n) : (u16)0;
        }
        *(uint4*)&WT[loc] = *(uint4*)out;
    }
}

// ---------- rope epilogue: acc holds 64 rope cols for 128 rows; partner via shfl ----------
static __device__ __forceinline__ void rope_epi(
    f32x4 (&acc)[2][4], bf16* __restrict__ dst, int m0, int w, int g, int lr, int tid, bool scaleq)
{
    const float SCv = 0.11785113019775793f;   // 1/sqrt(72)
    #pragma unroll
    for (int mt = 0; mt < 2; ++mt)
    #pragma unroll
    for (int r = 0; r < 4; ++r) {
        int gm = m0 + w * 32 + mt * 16 + g * 4 + r;
        int s = gm & 2047, b = gm >> 11;
        float ang = (float)s * exp2f(-(float)(lr & 3) * 3.3219280948873623f);
        float sn, cs;
        sincosf(ang, &sn, &cs);
        #pragma unroll
        for (int nt = 0; nt < 4; ++nt) {
            float v = acc[mt][nt][r];
            float pt = __shfl_xor(v, 4);
            float o = (lr & 4) ? fmaf(pt, sn, v * cs) : fmaf(-pt, sn, v * cs);
            if (scaleq) o *= SCv;
            int h = (nt * 16 + lr) >> 3, j = lr & 7;
            dst[((size_t)(b * NH + h) * SEQ + s) * DQKPAD + 64 + j] = __float2bfloat16(o);
        }
    }
    // zero pads [72,96) for all 8 heads of these 128 rows
    for (int u = tid; u < 128 * 96; u += 256) {
        int rw = u / 96, rem = u - rw * 96;
        int h = rem / 12, c = rem - h * 12;
        int row = m0 + rw, b2 = row >> 11, s2 = row & 2047;
        *(unsigned int*)&dst[((size_t)(b2 * NH + h) * SEQ + s2) * DQKPAD + 72 + c * 2] = 0u;
    }
}

// ------- 128x64 bf16 MFMA GEMM body, BK=64, global_load_lds staging + XOR swizzle -------
// modes: 0 bf16->C0 (n0==640: kr-rope -> kv_k); 1 dual->C0/C0f;
// 3 KV-scatter (K direct, V via LDS transpose); 4 Q-scatter scaled (n0==512: q-rope).
static __device__ __forceinline__ void gemm_body(
    int bx, int by,
    const bf16* __restrict__ A, int lda,
    const bf16* __restrict__ BT, int ldb,
    int N, int Kpad, int mode,
    void* __restrict__ C0, int ldc,
    bf16* __restrict__ kv_k, bf16* __restrict__ kv_v,
    const int* __restrict__ flagp, float* __restrict__ C0f,
    bf16* LB)
{
    bf16* Al = LB;
    bf16* Bl = LB + 128 * 64;
    const int tid = threadIdx.x;
    const int m0 = by * 128, n0 = bx * 64;
    const int lane = tid & 63, w = tid >> 6;
    const int g = lane >> 4, lr = lane & 15;
    f32x4 acc[2][4] = {};
    const int r8 = lane >> 3;
    const int xr8 = ((lane & 7) ^ r8) * 8;     // pre-swizzled source column (elems)
    const int swx = (lr & 7) << 4;             // read-side XOR (bytes)

    for (int k0 = 0; k0 < Kpad; k0 += 64) {
        #pragma unroll
        for (int i = 0; i < 4; ++i)
            GL16(&A[(size_t)(m0 + w * 32 + i * 8 + r8) * lda + k0 + xr8],
                 (char*)Al + w * 4096 + i * 1024);
        #pragma unroll
        for (int i = 0; i < 2; ++i)
            GL16(&BT[(size_t)(n0 + w * 16 + i * 8 + r8) * ldb + k0 + xr8],
                 (char*)Bl + w * 2048 + i * 1024);
        __syncthreads();
        #pragma unroll
        for (int ks = 0; ks < 2; ++ks) {
            const int cs = (ks * 64 + g * 16) ^ swx;
            bf16x8 a0 = ld_bf8((const bf16*)((const char*)Al + (w * 32 + lr) * 128 + cs));
            bf16x8 a1 = ld_bf8((const bf16*)((const char*)Al + (w * 32 + 16 + lr) * 128 + cs));
            #pragma unroll
            for (int nt = 0; nt < 4; ++nt) {
                bf16x8 b = ld_bf8((const bf16*)((const char*)Bl + (nt * 16 + lr) * 128 + cs));
                acc[0][nt] = __builtin_amdgcn_mfma_f32_16x16x32_bf16(a0, b, acc[0][nt], 0, 0, 0);
                acc[1][nt] = __builtin_amdgcn_mfma_f32_16x16x32_bf16(a1, b, acc[1][nt], 0, 0, 0);
            }
        }
        __syncthreads();
    }

    if (mode == 0 && n0 == 640) {       // kr-rope block (unscaled) -> k_attn
        rope_epi(acc, kv_k, m0, w, g, lr, tid, false);
        return;
    }
    if (mode == 4 && n0 == DM) {        // qr-rope block (scaled) -> q_attn
        rope_epi(acc, (bf16*)C0, m0, w, g, lr, tid, true);
        return;
    }
    if (mode == 3 && n0 >= DM) {
        // V block: LDS transpose -> coalesced V^T rows
        const int h = (n0 - DM) >> 6;
        const int b = m0 >> 11, s0 = m0 & 2047;
        bf16* T = LB;   // [64][stride 136]
        #pragma unroll
        for (int mt = 0; mt < 2; ++mt)
        #pragma unroll
        for (int nt = 0; nt < 4; ++nt)
        #pragma unroll
        for (int r = 0; r < 4; ++r) {
            int dv = nt * 16 + lr;
            int sl = w * 32 + mt * 16 + g * 4 + r;
            T[dv * 136 + sl] = __float2bfloat16(acc[mt][nt][r]);
        }
        __syncthreads();
        const int row = tid >> 2, coff = (tid & 3) * 32;
        bf16* dst = &kv_v[((size_t)(b * NH + h) * DHD + row) * SEQ + s0 + coff];
        const bf16* srcp = &T[row * 136 + coff];
        #pragma unroll
        for (int q2 = 0; q2 < 4; ++q2)
            *(uint4*)(dst + q2 * 8) = *(const uint4*)(srcp + q2 * 8);
        return;
    }

    const float SCv = 0.11785113019775793f;
    const int f32o = (mode == 1 && flagp) ? *flagp : 0;
    #pragma unroll
    for (int mt = 0; mt < 2; ++mt)
    #pragma unroll
    for (int nt = 0; nt < 4; ++nt)
    #pragma unroll
    for (int r = 0; r < 4; ++r) {
        int gm = m0 + w * 32 + mt * 16 + g * 4 + r;
        int gn = n0 + nt * 16 + lr;
        float v = acc[mt][nt][r];
        if (mode == 0) {
            ((bf16*)C0)[(size_t)gm * ldc + gn] = __float2bfloat16(v);
        } else if (mode == 1) {
            if (f32o) C0f[(size_t)gm * ldc + gn] = v;
            else ((bf16*)C0)[(size_t)gm * ldc + gn] = __float2bfloat16(v);
        } else if (mode == 4) {
            int b = gm >> 11, s = gm & 2047;
            int h = gn >> 6, dh = gn & 63;
            ((bf16*)C0)[((size_t)(b * NH + h) * SEQ + s) * DQKPAD + dh] = __float2bfloat16(v * SCv);
        } else { // mode 3 K block: direct scatter [bh][s][96]
            int b = gm >> 11, s = gm & 2047;
            int h = gn >> 6, dh = gn & 63;
            kv_k[((size_t)(b * NH + h) * SEQ + s) * DQKPAD + dh] = __float2bfloat16(v);
        }
    }
}

__global__ __launch_bounds__(256) void gemm128(
    const bf16* __restrict__ A, int lda,
    const bf16* __restrict__ BT, int ldb,
    int N, int Kpad, int mode,
    void* __restrict__ C0, int ldc,
    bf16* __restrict__ kv_k, bf16* __restrict__ kv_v,
    const int* __restrict__ flagp, float* __restrict__ C0f)
{
    __shared__ __align__(16) bf16 LB[128 * 64 + 64 * 64];   // Al 16KB | Bl 8KB
    gemm_body(blockIdx.x, blockIdx.y, A, lda, BT, ldb, N, Kpad, mode,
              C0, ldc, kv_k, kv_v, flagp, C0f, LB);
}

// ---- merged up-projections: blocks 0..8 = uq (N=576,K=256), 9..24 = ukv (N=1024,K=384) ----
__global__ __launch_bounds__(256) void gemm_dual(
    const bf16* __restrict__ A1, const bf16* __restrict__ BT1, void* __restrict__ C1,
    const bf16* __restrict__ A2, const bf16* __restrict__ BT2,
    bf16* __restrict__ kv_k, bf16* __restrict__ kv_v)
{
    __shared__ __align__(16) bf16 LB[128 * 64 + 64 * 64];
    if (blockIdx.x < 9) {
        gemm_body(blockIdx.x, blockIdx.y, A1, QP, BT1, QP, 576, QP, 4,
                  C1, 0, nullptr, nullptr, nullptr, nullptr, LB);
    } else {
        gemm_body(blockIdx.x - 9, blockIdx.y, A2, 384, BT2, 384, 1024, 384, 3,
                  nullptr, 0, kv_k, kv_v, nullptr, nullptr, LB);
    }
}

// ------- merged layernorms, one wave per row (bf16 y input) -------
__global__ __launch_bounds__(256) void ln_both(
    const bf16* __restrict__ y,
    const bf16* __restrict__ qg, const bf16* __restrict__ qb,
    const bf16* __restrict__ kg, const bf16* __restrict__ kb,
    bf16* __restrict__ cq, bf16* __restrict__ ckv_b, float* __restrict__ ckv_f,
    bf16* __restrict__ ckvp, const int* __restrict__ flagp)
{
    const int w = threadIdx.x >> 6, lane = threadIdx.x & 63;
    const int blk = blockIdx.x;
    if (blk < 1024) {
        const int row = blk * 4 + w;
        const bf16* yr = y + (size_t)row * 704;
        float s = 0.f, ss = 0.f;
        for (int i = lane; i < 256; i += 64) { float v = __bfloat162float(yr[i]); s += v; ss += v * v; }
        #pragma unroll
        for (int m = 1; m < 64; m <<= 1) { s += __shfl_xor(s, m); ss += __shfl_xor(ss, m); }
        float mean = s * (1.f / 256.f);
        float var = ss * (1.f / 256.f) - mean * mean;
        float rstd = rsqrtf(var + 1e-5f);
        for (int i = lane; i < 256; i += 64) {
            float v = (__bfloat162float(yr[i]) - mean) * rstd * __bfloat162float(qg[i]) + __bfloat162float(qb[i]);
            cq[(size_t)row * 256 + i] = __float2bfloat16(v);
        }
    } else {
        const int row = (blk - 1024) * 4 + w;
        const bf16* yr = y + (size_t)row * 704 + 256;
        const int f32o = *flagp;
        float s = 0.f, ss = 0.f;
        for (int i = lane; i < KVP; i += 64) { float v = __bfloat162float(yr[i]); s += v; ss += v * v; }
        #pragma unroll
        for (int m = 1; m < 64; m <<= 1) { s += __shfl_xor(s, m); ss += __shfl_xor(ss, m); }
        float mean = s * (1.f / 341.f);
        float var = ss * (1.f / 341.f) - mean * mean;
        float rstd = rsqrtf(var + 1e-5f);
        for (int i = lane; i < KVP; i += 64) {
            float v = (__bfloat162float(yr[i]) - mean) * rstd * __bfloat162float(kg[i]) + __bfloat162float(kb[i]);
            if (f32o) ckv_f[(size_t)row * KVP + i] = v;
            else ckv_b[(size_t)row * KVP + i] = __float2bfloat16(v);
            ckvp[(size_t)row * 384 + i] = __float2bfloat16(v);
        }
        for (int i = KVP + lane; i < 384; i += 64) ckvp[(size_t)row * 384 + i] = __float2bfloat16(0.f);
    }
}

// ---- causal flash attention: 4-way split-KV + qb-pairing + swapped QK^T
//      + defer-max + T14 async-STAGE + T2 Kl-swizzle + T5 setprio ----
// m/l partials in interleaved [bh][q][4] layout (float4 for combine).
__global__ __launch_bounds__(256) void attn_split3(
    const bf16* __restrict__ qa, const bf16* __restrict__ ka, const bf16* __restrict__ vat,
    bf16* __restrict__ po, float* __restrict__ mlm, float* __restrict__ mll)
{
    __shared__ __align__(16) bf16 Kl[64][128];   // 16 swizzled 8-elem slots (12 used)
    __shared__ __align__(16) bf16 Vt[64][72];
    __shared__ __align__(16) bf16 Pl[4][16][72];
    const int sp = blockIdx.x, pr = blockIdx.y, bh = blockIdx.z;
    const int tid = threadIdx.x, w = tid >> 6, lane = tid & 63;
    const int g = lane >> 4, lr = lane & 15;
    const size_t base = (size_t)bh * SEQ;
    const float L2E = 1.4426950408889634f;
    const bf16* vb = vat + (size_t)bh * DHD * SEQ;

    uint4 kreg0, kreg1, kreg2, vreg0, vreg1;
    const int vd = tid >> 2, vko = (tid & 3) * 16;
    const int kr0 = tid / 12,          ks0 = tid % 12;
    const int kr1 = (tid + 256) / 12,  ks1 = (tid + 256) % 12;
    const int kr2 = (tid + 512) / 12,  ks2 = (tid + 512) % 12;
    const int kx0 = (ks0 ^ (kr0 & 15)) * 8;
    const int kx1 = (ks1 ^ (kr1 & 15)) * 8;
    const int kx2 = (ks2 ^ (kr2 & 15)) * 8;

    #define ISSUE_KV(j0)  do { \
        kreg0 = *(const uint4*)&ka[(base + (j0) + kr0) * DQKPAD + ks0 * 8]; \
        kreg1 = *(const uint4*)&ka[(base + (j0) + kr1) * DQKPAD + ks1 * 8]; \
        kreg2 = *(const uint4*)&ka[(base + (j0) + kr2) * DQKPAD + ks2 * 8]; \
        const bf16* vsrc = &vb[(size_t)vd * SEQ + (j0) + vko]; \
        vreg0 = *(const uint4*)vsrc; vreg1 = *(const uint4*)(vsrc + 8); \
    } while (0)

    for (int half = 0; half < 2; ++half) {
        const int qb = half ? (31 - pr) : pr;
        const int qrow0 = qb * 64 + w * 16;
        const int myq = qrow0 + lr;

        bf16x8 qf[3];
        #pragma unroll
        for (int kc = 0; kc < 3; ++kc)
            qf[kc] = ld_bf8(&qa[(base + myq) * DQKPAD + kc * 32 + g * 8]);

        float m_p = -1e30f, l_p = 0.f;
        f32x4 acc_o[4] = {};
        const int ng = qb + 1;
        const int bs = (ng * sp) >> 2, be = (ng * (sp + 1)) >> 2;

        if (bs < be) ISSUE_KV(bs * 64);

        for (int gi = bs; gi < be; ++gi) {
            const int j0 = gi * 64;
            __syncthreads();
            *(uint4*)&Kl[kr0][kx0] = kreg0;
            *(uint4*)&Kl[kr1][kx1] = kreg1;
            *(uint4*)&Kl[kr2][kx2] = kreg2;
            *(uint4*)&Vt[vd][vko]     = vreg0;
            *(uint4*)&Vt[vd][vko + 8] = vreg1;
            __syncthreads();
            if (gi + 1 < be) ISSUE_KV(j0 + 64);

            f32x4 accs[4] = {};
            __builtin_amdgcn_s_setprio(1);
            #pragma unroll
            for (int kc = 0; kc < 3; ++kc) {
                #pragma unroll
                for (int nt = 0; nt < 4; ++nt) {
                    bf16x8 kf = ld_bf8(&Kl[nt * 16 + lr][((kc * 4 + g) ^ lr) * 8]);
                    accs[nt] = __builtin_amdgcn_mfma_f32_16x16x32_bf16(kf, qf[kc], accs[nt], 0, 0, 0);
                }
            }
            __builtin_amdgcn_s_setprio(0);
            float s_[4][4];
            float mloc = -1e30f;
            if (j0 + 63 > qrow0) {
                #pragma unroll
                for (int nt = 0; nt < 4; ++nt)
                #pragma unroll
                for (int r = 0; r < 4; ++r) {
                    int key = j0 + nt * 16 + g * 4 + r;
                    float sv = accs[nt][r];
                    sv = (key <= myq) ? sv : -1e30f;
                    s_[nt][r] = sv;
                    mloc = fmaxf(mloc, sv);
                }
            } else {
                #pragma unroll
                for (int nt = 0; nt < 4; ++nt)
                #pragma unroll
                for (int r = 0; r < 4; ++r) {
                    float sv = accs[nt][r];
                    s_[nt][r] = sv;
                    mloc = fmaxf(mloc, sv);
                }
            }
            mloc = fmaxf(mloc, __shfl_xor(mloc, 16));
            mloc = fmaxf(mloc, __shfl_xor(mloc, 32));

            if (__all(mloc <= m_p + 8.f)) {
                float rs = 0.f;
                #pragma unroll
                for (int nt = 0; nt < 4; ++nt)
                #pragma unroll
                for (int r = 0; r < 4; ++r) {
                    float p = exp2f((s_[nt][r] - m_p) * L2E);
                    s_[nt][r] = p; rs += p;
                }
                rs += __shfl_xor(rs, 16);
                rs += __shfl_xor(rs, 32);
                l_p += rs;
            } else {
                float mn = fmaxf(m_p, mloc);
                float alpha = exp2f((m_p - mn) * L2E);
                m_p = mn;
                float rs = 0.f;
                #pragma unroll
                for (int nt = 0; nt < 4; ++nt)
                #pragma unroll
                for (int r = 0; r < 4; ++r) {
                    float p = exp2f((s_[nt][r] - mn) * L2E);
                    s_[nt][r] = p; rs += p;
                }
                rs += __shfl_xor(rs, 16);
                rs += __shfl_xor(rs, 32);
                l_p = l_p * alpha + rs;
                float ar[4];
                #pragma unroll
                for (int r = 0; r < 4; ++r) ar[r] = __shfl(alpha, g * 4 + r);
                #pragma unroll
                for (int nv = 0; nv < 4; ++nv)
                #pragma unroll
                for (int r = 0; r < 4; ++r) acc_o[nv][r] *= ar[r];
            }
            #pragma unroll
            for (int nt = 0; nt < 4; ++nt) {
                ushort4 pk;
                pk.x = __builtin_bit_cast(u16, __float2bfloat16(s_[nt][0]));
                pk.y = __builtin_bit_cast(u16, __float2bfloat16(s_[nt][1]));
                pk.z = __builtin_bit_cast(u16, __float2bfloat16(s_[nt][2]));
                pk.w = __builtin_bit_cast(u16, __float2bfloat16(s_[nt][3]));
                *(ushort4*)&Pl[w][lr][nt * 16 + g * 4] = pk;
            }
            bf16x8 pf0 = ld_bf8(&Pl[w][lr][g * 8]);
            bf16x8 pf1 = ld_bf8(&Pl[w][lr][32 + g * 8]);
            __builtin_amdgcn_s_setprio(1);
            #pragma unroll
            for (int nv = 0; nv < 4; ++nv) {
                bf16x8 vf0 = ld_bf8(&Vt[nv * 16 + lr][g * 8]);
                acc_o[nv] = __builtin_amdgcn_mfma_f32_16x16x32_bf16(pf0, vf0, acc_o[nv], 0, 0, 0);
                bf16x8 vf1 = ld_bf8(&Vt[nv * 16 + lr][32 + g * 8]);
                acc_o[nv] = __builtin_amdgcn_mfma_f32_16x16x32_bf16(pf1, vf1, acc_o[nv], 0, 0, 0);
            }
            __builtin_amdgcn_s_setprio(0);
        }

        const size_t pb = (size_t)(bh * NSPLIT + sp) * SEQ;
        #pragma unroll
        for (int r = 0; r < 4; ++r) {
            int qrow = qrow0 + g * 4 + r;
            #pragma unroll
            for (int nv = 0; nv < 4; ++nv)
                po[(pb + qrow) * DHD + nv * 16 + lr] = __float2bfloat16(acc_o[nv][r]);
        }
        if (lane < 16) {
            size_t mi = ((size_t)bh * SEQ + qrow0 + lane) * 4 + sp;
            mlm[mi] = m_p;
            mll[mi] = l_p;
        }
    }
    #undef ISSUE_KV
}

// ---------------- combine split partials -> attn_o [b][s][h*64+d] ----------------
__global__ __launch_bounds__(256) void attn_combine(
    const bf16* __restrict__ po, const float* __restrict__ mlm, const float* __restrict__ mll,
    bf16* __restrict__ ao)
{
    int id = blockIdx.x * 256 + threadIdx.x;   // 16*2048*8 = 262144
    int bh = id >> 14;
    int rem = id & 16383;
    int q = rem >> 3, dc = (rem & 7) * 8;
    const float L2E = 1.4426950408889634f;
    size_t mi = ((size_t)bh * SEQ + q) * 4;
    f32x4 ms = *(const f32x4*)&mlm[mi];
    f32x4 ls = *(const f32x4*)&mll[mi];
    float M = fmaxf(fmaxf(ms[0], ms[1]), fmaxf(ms[2], ms[3]));
    float wsc[NSPLIT]; float L = 0.f;
    #pragma unroll
    for (int s = 0; s < NSPLIT; ++s) { wsc[s] = exp2f((ms[s] - M) * L2E); L += wsc[s] * ls[s]; }
    float o[8] = {};
    #pragma unroll
    for (int s = 0; s < NSPLIT; ++s) {
        if (ls[s] <= 0.f) continue;
        bf16x8 pv = ld_bf8(&po[((size_t)(bh * NSPLIT + s) * SEQ + q) * DHD + dc]);
        #pragma unroll
        for (int j = 0; j < 8; ++j) o[j] += wsc[s] * (float)pv[j];
    }
    float invL = 1.f / L;
    int b = bh >> 3, h = bh & 7;
    __bf16 tmp[8];
    #pragma unroll
    for (int j = 0; j < 8; ++j) tmp[j] = (__bf16)(o[j] * invL);
    *(uint4*)&ao[((size_t)(b * SEQ) + q) * DM + h * DHD + dc] = *(uint4*)tmp;
}

extern "C" void kernel_launch(void* const* d_in, const int* in_sizes, int n_in,
                              void* d_out, int out_size, void* d_ws, size_t ws_size,
                              hipStream_t stream) {
    char* ws = (char*)d_ws;
    bf16* AR      = (bf16*)(ws + 0);              // arena: x | W_o | params
    float* ml_m   = (float*)(ws + 0);             // alias x region (dead after x-gemm), 512KB
    float* ml_l   = (float*)(ws + 1048576);       // 512KB
    bf16* WT      = (bf16*)(ws + 6391296);        // transposed weights (1,802,240 B)
    int*  flagp   = (int*)(ws + 8193536);
    bf16* y       = (bf16*)(ws + 8194048);        // fused x-proj out [4096][704] bf16
    bf16* cq      = (bf16*)(ws + 19728384);       // [4096][256]
    bf16* ckvp    = (bf16*)(ws + 21825536);       // [4096][384]
    bf16* q_attn  = (bf16*)(ws + 26019840);
    bf16* k_attn  = (bf16*)(ws + 32311296);
    bf16* v_attnT = (bf16*)(ws + 38602752);
    bf16* attn_o  = (bf16*)(ws + 42797056);
    bf16* po      = (bf16*)(ws + 50331648);       // 4-split partials, 16,777,216 B

    const bf16* xb  = AR + OFF_X;
    const bf16* W_o = AR + OFF_WO;
    const bf16* qg  = AR + OFF_QG;
    const bf16* qb_ = AR + OFF_QB;
    const bf16* kg  = AR + OFF_KG;
    const bf16* kb  = AR + OFF_KB;

    bf16*  out_b = (bf16*)d_out;
    float* out_f = (float*)d_out;
    bf16*  ckv_b = out_b + (size_t)MROWS * DM;
    float* ckv_f = out_f + (size_t)MROWS * DM;

    dim3 blk(256);
    // 1) prep: flag + convert + weight transposes (8-wide)
    prep<<<dim3((G_TOT + 255) / 256), blk, 0, stream>>>(
        d_in[0], d_in[1], d_in[2], d_in[3], d_in[4], d_in[5],
        d_in[6], d_in[7], d_in[8], d_in[9], d_in[10], d_in[11],
        (u16*)AR, (u16*)WT, flagp);
    // 2) fused x-proj [dq|dkv|kr] N=704, bf16 y (n0==640 block does kr-rope -> k_attn)
    gemm128<<<dim3(11, 32), blk, 0, stream>>>(xb, DM, WT + T_DQ, DM, 704, DM, 0, y, 704, k_attn, nullptr, nullptr, nullptr);
    // 3) merged layernorms (bf16 y in)
    ln_both<<<dim3(2048), blk, 0, stream>>>(y, qg, qb_, kg, kb, cq, ckv_b, ckv_f, ckvp, flagp);
    // 4+5) merged up-projections: uq (q-rope) + ukv (K/V^T scatter)
    gemm_dual<<<dim3(25, 32), blk, 0, stream>>>(cq, WT + T_UQ, q_attn, ckvp, WT + T_UKV, k_attn, v_attnT);
    // 6) attention (4-way split-KV, qb-paired, swapped-softmax, defer-max, T14, T2, T5)
    attn_split3<<<dim3(NSPLIT, 16, 16), blk, 0, stream>>>(q_attn, k_attn, v_attnT, po, ml_m, ml_l);
    // 7) combine (float4 m/l)
    attn_combine<<<dim3(1024), blk, 0, stream>>>(po, ml_m, ml_l, attn_o);
    // 8) output projection -> d_out (dual dtype)
    gemm128<<<dim3(8, 32), blk, 0, stream>>>(attn_o, DM, W_o, DM, DM, DM, 1, out_b, DM, nullptr, nullptr, flagp, out_f);
}

// Round 18
// 109.910 us; speedup vs baseline: 1.6158x; 1.0099x over previous
//
#include <hip/hip_runtime.h>
#include <hip/hip_bf16.h>

#define BATCH 2
#define SEQ 2048
#define DM 512
#define NH 8
#define DHD 64
#define QP 256
#define KVP 341
#define DQKPAD 96
#define MROWS 4096   // BATCH*SEQ

// bf16 arena element offsets (x, W_o, LN params only)
#define OFF_X     0
#define OFF_WO    2932224
#define OFF_QG    3194368
#define OFF_QB    3194624
#define OFF_KG    3194880
#define OFF_KB    3195221

// transposed-weight arena element offsets ([N][K])
#define T_DQ   0        // [256][512]
#define T_DKV  131072   // [384][512] (n>=341 zero)
#define T_KR   327680   // [64][512]
#define T_UQ   360448   // [512][256]
#define T_QR   491520   // [64][256]
#define T_UKV  507904   // [1024][384] (k>=341 zero)
#define T_TOT  901120

#define NW_X   2097152
#define NW_WO  262144
#define NW_PAR 1194

// prep work groups (8 elems each)
#define G_X   262144
#define G_WO  32768
#define G_PAR 150
#define G_WT  112640
#define G_TOT (G_X + G_WO + G_PAR + G_WT)

#define NSPLIT 4

typedef __bf16 bf16x8 __attribute__((ext_vector_type(8)));
typedef float f32x4 __attribute__((ext_vector_type(4)));
typedef __hip_bfloat16 bf16;
typedef unsigned short u16;

static __device__ __forceinline__ bf16x8 ld_bf8(const bf16* p) {
    return __builtin_bit_cast(bf16x8, *(const uint4*)p);
}

// async global->LDS, 16B per lane; LDS dest = wave-uniform base + lane*16
#define GL16(gp, lp) __builtin_amdgcn_global_load_lds( \
    (const __attribute__((address_space(1))) void*)(gp), \
    (__attribute__((address_space(3))) void*)(lp), 16, 0, 0)

// ---------- prep: dtype-flag + convert x/W_o/params + weight transposes (8-wide) ----------
__global__ __launch_bounds__(256) void prep(
    const void* px, const void* pwdq, const void* pwuq, const void* pwqr,
    const void* pwdkv, const void* pwukv, const void* pwkr, const void* pwo,
    const void* pqg, const void* pqb, const void* pkg, const void* pkb,
    u16* __restrict__ arena, u16* __restrict__ WT, int* __restrict__ flagp)
{
    __shared__ int cnt;
    if (threadIdx.x == 0) cnt = 0;
    __syncthreads();
    int bad = 0;
    const u16* xs = (const u16*)px;
    for (int i = threadIdx.x; i < 2048; i += 256) {
        u16 u = xs[i];
        int e = (u >> 7) & 0xFF;
        if (u != 0 && (e < 90 || e > 164)) bad++;
    }
    #pragma unroll
    for (int m2 = 1; m2 < 64; m2 <<= 1) bad += __shfl_xor(bad, m2);
    if ((threadIdx.x & 63) == 0) atomicAdd(&cnt, bad);
    __syncthreads();
    const int f = (cnt > 256) ? 1 : 0;   // 1 => inputs are fp32
    if (blockIdx.x == 0 && threadIdx.x == 0) *flagp = f;

    int gid = blockIdx.x * 256 + threadIdx.x;
    if (gid >= G_TOT) return;

    auto rdu = [&](const void* s, int i) -> u16 {
        if (f) return __builtin_bit_cast(u16, __float2bfloat16(((const float*)s)[i]));
        return ((const u16*)s)[i];
    };

    if (gid < G_X + G_WO) {
        const void* src = (gid < G_X) ? px : pwo;
        int base = (gid < G_X) ? OFF_X : OFF_WO;
        int i = (gid < G_X) ? gid : gid - G_X;
        u16 out[8];
        if (f) {
            const float* s = (const float*)src + i * 8;
            #pragma unroll
            for (int j = 0; j < 8; ++j) out[j] = __builtin_bit_cast(u16, __float2bfloat16(s[j]));
        } else {
            *(uint4*)out = ((const uint4*)src)[i];
        }
        *(uint4*)&arena[base + i * 8] = *(uint4*)out;
    } else if (gid < G_X + G_WO + G_PAR) {
        int i0 = (gid - G_X - G_WO) * 8;
        for (int j = 0; j < 8; ++j) {
            int i = i0 + j;
            if (i >= NW_PAR) break;
            if (i < 256)      arena[OFF_QG + i]         = rdu(pqg, i);
            else if (i < 512) arena[OFF_QB + (i - 256)] = rdu(pqb, i - 256);
            else if (i < 853) arena[OFF_KG + (i - 512)] = rdu(pkg, i - 512);
            else              arena[OFF_KB + (i - 853)] = rdu(pkb, i - 853);
        }
    } else {
        int loc = (gid - (G_X + G_WO + G_PAR)) * 8;   // 8 consecutive: same n, k0..k0+7
        const void* src; int n, k0, sN, klim, nok;
        if (loc < T_DKV)      { int l = loc;          n = l >> 9; k0 = l & 511; src = pwdq;  sN = 256;  klim = 512; nok = 1; }
        else if (loc < T_KR)  { int l = loc - T_DKV;  n = l >> 9; k0 = l & 511; src = pwdkv; sN = 341;  klim = 512; nok = (n < 341); }
        else if (loc < T_UQ)  { int l = loc - T_KR;   n = l >> 9; k0 = l & 511; src = pwkr;  sN = 64;   klim = 512; nok = 1; }
        else if (loc < T_QR)  { int l = loc - T_UQ;   n = l >> 8; k0 = l & 255; src = pwuq;  sN = 512;  klim = 256; nok = 1; }
        else if (loc < T_UKV) { int l = loc - T_QR;   n = l >> 8; k0 = l & 255; src = pwqr;  sN = 64;   klim = 256; nok = 1; }
        else                  { int l = loc - T_UKV;  n = l / 384; k0 = l % 384; src = pwukv; sN = 1024; klim = 341; nok = 1; }
        u16 out[8];
        #pragma unroll
        for (int j = 0; j < 8; ++j) {
            int k = k0 + j;
            out[j] = (nok && k < klim) ? rdu(src, k * sN + n) : (u16)0;
        }
        *(uint4*)&WT[loc] = *(uint4*)out;
    }
}

// ---------- rope epilogue: acc holds 64 rope cols for 128 rows; partner via shfl ----------
static __device__ __forceinline__ void rope_epi(
    f32x4 (&acc)[2][4], bf16* __restrict__ dst, int m0, int w, int g, int lr, int tid, bool scaleq)
{
    const float SCv = 0.11785113019775793f;   // 1/sqrt(72)
    #pragma unroll
    for (int mt = 0; mt < 2; ++mt)
    #pragma unroll
    for (int r = 0; r < 4; ++r) {
        int gm = m0 + w * 32 + mt * 16 + g * 4 + r;
        int s = gm & 2047, b = gm >> 11;
        float ang = (float)s * exp2f(-(float)(lr & 3) * 3.3219280948873623f);
        float sn, cs;
        sincosf(ang, &sn, &cs);
        #pragma unroll
        for (int nt = 0; nt < 4; ++nt) {
            float v = acc[mt][nt][r];
            float pt = __shfl_xor(v, 4);
            float o = (lr & 4) ? fmaf(pt, sn, v * cs) : fmaf(-pt, sn, v * cs);
            if (scaleq) o *= SCv;
            int h = (nt * 16 + lr) >> 3, j = lr & 7;
            dst[((size_t)(b * NH + h) * SEQ + s) * DQKPAD + 64 + j] = __float2bfloat16(o);
        }
    }
    // zero pads [72,96) for all 8 heads of these 128 rows
    for (int u = tid; u < 128 * 96; u += 256) {
        int rw = u / 96, rem = u - rw * 96;
        int h = rem / 12, c = rem - h * 12;
        int row = m0 + rw, b2 = row >> 11, s2 = row & 2047;
        *(unsigned int*)&dst[((size_t)(b2 * NH + h) * SEQ + s2) * DQKPAD + 72 + c * 2] = 0u;
    }
}

// ------- 128x64 bf16 MFMA GEMM body, BK=64, global_load_lds staging + XOR swizzle -------
// modes: 0 bf16->C0 (n0==640: kr-rope -> kv_k); 1 dual->C0/C0f;
// 3 KV-scatter (K direct, V via LDS transpose); 4 Q-scatter scaled (n0==512: q-rope).
static __device__ __forceinline__ void gemm_body(
    int bx, int by,
    const bf16* __restrict__ A, int lda,
    const bf16* __restrict__ BT, int ldb,
    int N, int Kpad, int mode,
    void* __restrict__ C0, int ldc,
    bf16* __restrict__ kv_k, bf16* __restrict__ kv_v,
    const int* __restrict__ flagp, float* __restrict__ C0f,
    bf16* LB)
{
    bf16* Al = LB;
    bf16* Bl = LB + 128 * 64;
    const int tid = threadIdx.x;
    const int m0 = by * 128, n0 = bx * 64;
    const int lane = tid & 63, w = tid >> 6;
    const int g = lane >> 4, lr = lane & 15;
    f32x4 acc[2][4] = {};
    const int r8 = lane >> 3;
    const int xr8 = ((lane & 7) ^ r8) * 8;     // pre-swizzled source column (elems)
    const int swx = (lr & 7) << 4;             // read-side XOR (bytes)

    for (int k0 = 0; k0 < Kpad; k0 += 64) {
        #pragma unroll
        for (int i = 0; i < 4; ++i)
            GL16(&A[(size_t)(m0 + w * 32 + i * 8 + r8) * lda + k0 + xr8],
                 (char*)Al + w * 4096 + i * 1024);
        #pragma unroll
        for (int i = 0; i < 2; ++i)
            GL16(&BT[(size_t)(n0 + w * 16 + i * 8 + r8) * ldb + k0 + xr8],
                 (char*)Bl + w * 2048 + i * 1024);
        __syncthreads();
        #pragma unroll
        for (int ks = 0; ks < 2; ++ks) {
            const int cs = (ks * 64 + g * 16) ^ swx;
            bf16x8 a0 = ld_bf8((const bf16*)((const char*)Al + (w * 32 + lr) * 128 + cs));
            bf16x8 a1 = ld_bf8((const bf16*)((const char*)Al + (w * 32 + 16 + lr) * 128 + cs));
            #pragma unroll
            for (int nt = 0; nt < 4; ++nt) {
                bf16x8 b = ld_bf8((const bf16*)((const char*)Bl + (nt * 16 + lr) * 128 + cs));
                acc[0][nt] = __builtin_amdgcn_mfma_f32_16x16x32_bf16(a0, b, acc[0][nt], 0, 0, 0);
                acc[1][nt] = __builtin_amdgcn_mfma_f32_16x16x32_bf16(a1, b, acc[1][nt], 0, 0, 0);
            }
        }
        __syncthreads();
    }

    if (mode == 0 && n0 == 640) {       // kr-rope block (unscaled) -> k_attn
        rope_epi(acc, kv_k, m0, w, g, lr, tid, false);
        return;
    }
    if (mode == 4 && n0 == DM) {        // qr-rope block (scaled) -> q_attn
        rope_epi(acc, (bf16*)C0, m0, w, g, lr, tid, true);
        return;
    }
    if (mode == 3 && n0 >= DM) {
        // V block: LDS transpose -> coalesced V^T rows
        const int h = (n0 - DM) >> 6;
        const int b = m0 >> 11, s0 = m0 & 2047;
        bf16* T = LB;   // [64][stride 136]
        #pragma unroll
        for (int mt = 0; mt < 2; ++mt)
        #pragma unroll
        for (int nt = 0; nt < 4; ++nt)
        #pragma unroll
        for (int r = 0; r < 4; ++r) {
            int dv = nt * 16 + lr;
            int sl = w * 32 + mt * 16 + g * 4 + r;
            T[dv * 136 + sl] = __float2bfloat16(acc[mt][nt][r]);
        }
        __syncthreads();
        const int row = tid >> 2, coff = (tid & 3) * 32;
        bf16* dst = &kv_v[((size_t)(b * NH + h) * DHD + row) * SEQ + s0 + coff];
        const bf16* srcp = &T[row * 136 + coff];
        #pragma unroll
        for (int q2 = 0; q2 < 4; ++q2)
            *(uint4*)(dst + q2 * 8) = *(const uint4*)(srcp + q2 * 8);
        return;
    }

    const float SCv = 0.11785113019775793f;
    const int f32o = (mode == 1 && flagp) ? *flagp : 0;
    #pragma unroll
    for (int mt = 0; mt < 2; ++mt)
    #pragma unroll
    for (int nt = 0; nt < 4; ++nt)
    #pragma unroll
    for (int r = 0; r < 4; ++r) {
        int gm = m0 + w * 32 + mt * 16 + g * 4 + r;
        int gn = n0 + nt * 16 + lr;
        float v = acc[mt][nt][r];
        if (mode == 0) {
            ((bf16*)C0)[(size_t)gm * ldc + gn] = __float2bfloat16(v);
        } else if (mode == 1) {
            if (f32o) C0f[(size_t)gm * ldc + gn] = v;
            else ((bf16*)C0)[(size_t)gm * ldc + gn] = __float2bfloat16(v);
        } else if (mode == 4) {
            int b = gm >> 11, s = gm & 2047;
            int h = gn >> 6, dh = gn & 63;
            ((bf16*)C0)[((size_t)(b * NH + h) * SEQ + s) * DQKPAD + dh] = __float2bfloat16(v * SCv);
        } else { // mode 3 K block: direct scatter [bh][s][96]
            int b = gm >> 11, s = gm & 2047;
            int h = gn >> 6, dh = gn & 63;
            kv_k[((size_t)(b * NH + h) * SEQ + s) * DQKPAD + dh] = __float2bfloat16(v);
        }
    }
}

__global__ __launch_bounds__(256) void gemm128(
    const bf16* __restrict__ A, int lda,
    const bf16* __restrict__ BT, int ldb,
    int N, int Kpad, int mode,
    void* __restrict__ C0, int ldc,
    bf16* __restrict__ kv_k, bf16* __restrict__ kv_v,
    const int* __restrict__ flagp, float* __restrict__ C0f)
{
    __shared__ __align__(16) bf16 LB[128 * 64 + 64 * 64];   // Al 16KB | Bl 8KB
    gemm_body(blockIdx.x, blockIdx.y, A, lda, BT, ldb, N, Kpad, mode,
              C0, ldc, kv_k, kv_v, flagp, C0f, LB);
}

// ---- merged up-projections: blocks 0..8 = uq (N=576,K=256), 9..24 = ukv (N=1024,K=384) ----
__global__ __launch_bounds__(256) void gemm_dual(
    const bf16* __restrict__ A1, const bf16* __restrict__ BT1, void* __restrict__ C1,
    const bf16* __restrict__ A2, const bf16* __restrict__ BT2,
    bf16* __restrict__ kv_k, bf16* __restrict__ kv_v)
{
    __shared__ __align__(16) bf16 LB[128 * 64 + 64 * 64];
    if (blockIdx.x < 9) {
        gemm_body(blockIdx.x, blockIdx.y, A1, QP, BT1, QP, 576, QP, 4,
                  C1, 0, nullptr, nullptr, nullptr, nullptr, LB);
    } else {
        gemm_body(blockIdx.x - 9, blockIdx.y, A2, 384, BT2, 384, 1024, 384, 3,
                  nullptr, 0, kv_k, kv_v, nullptr, nullptr, LB);
    }
}

// ------- merged layernorms, one wave per row (bf16 y input) -------
__global__ __launch_bounds__(256) void ln_both(
    const bf16* __restrict__ y,
    const bf16* __restrict__ qg, const bf16* __restrict__ qb,
    const bf16* __restrict__ kg, const bf16* __restrict__ kb,
    bf16* __restrict__ cq, bf16* __restrict__ ckv_b, float* __restrict__ ckv_f,
    bf16* __restrict__ ckvp, const int* __restrict__ flagp)
{
    const int w = threadIdx.x >> 6, lane = threadIdx.x & 63;
    const int blk = blockIdx.x;
    if (blk < 1024) {
        const int row = blk * 4 + w;
        const bf16* yr = y + (size_t)row * 704;
        float s = 0.f, ss = 0.f;
        for (int i = lane; i < 256; i += 64) { float v = __bfloat162float(yr[i]); s += v; ss += v * v; }
        #pragma unroll
        for (int m = 1; m < 64; m <<= 1) { s += __shfl_xor(s, m); ss += __shfl_xor(ss, m); }
        float mean = s * (1.f / 256.f);
        float var = ss * (1.f / 256.f) - mean * mean;
        float rstd = rsqrtf(var + 1e-5f);
        for (int i = lane; i < 256; i += 64) {
            float v = (__bfloat162float(yr[i]) - mean) * rstd * __bfloat162float(qg[i]) + __bfloat162float(qb[i]);
            cq[(size_t)row * 256 + i] = __float2bfloat16(v);
        }
    } else {
        const int row = (blk - 1024) * 4 + w;
        const bf16* yr = y + (size_t)row * 704 + 256;
        const int f32o = *flagp;
        float s = 0.f, ss = 0.f;
        for (int i = lane; i < KVP; i += 64) { float v = __bfloat162float(yr[i]); s += v; ss += v * v; }
        #pragma unroll
        for (int m = 1; m < 64; m <<= 1) { s += __shfl_xor(s, m); ss += __shfl_xor(ss, m); }
        float mean = s * (1.f / 341.f);
        float var = ss * (1.f / 341.f) - mean * mean;
        float rstd = rsqrtf(var + 1e-5f);
        for (int i = lane; i < KVP; i += 64) {
            float v = (__bfloat162float(yr[i]) - mean) * rstd * __bfloat162float(kg[i]) + __bfloat162float(kb[i]);
            if (f32o) ckv_f[(size_t)row * KVP + i] = v;
            else ckv_b[(size_t)row * KVP + i] = __float2bfloat16(v);
            ckvp[(size_t)row * 384 + i] = __float2bfloat16(v);
        }
        for (int i = KVP + lane; i < 384; i += 64) ckvp[(size_t)row * 384 + i] = __float2bfloat16(0.f);
    }
}

// ---- causal flash attention: 4-way split-KV + qb-pairing + swapped QK^T
//      + defer-max + T14 async-STAGE + T2 Kl-swizzle + T5 setprio ----
// m/l partials in interleaved [bh][q][4] layout (float4 for combine).
__global__ __launch_bounds__(256) void attn_split3(
    const bf16* __restrict__ qa, const bf16* __restrict__ ka, const bf16* __restrict__ vat,
    bf16* __restrict__ po, float* __restrict__ mlm, float* __restrict__ mll)
{
    __shared__ __align__(16) bf16 Kl[64][128];   // 16 swizzled 8-elem slots (12 used)
    __shared__ __align__(16) bf16 Vt[64][72];
    __shared__ __align__(16) bf16 Pl[4][16][72];
    const int sp = blockIdx.x, pr = blockIdx.y, bh = blockIdx.z;
    const int tid = threadIdx.x, w = tid >> 6, lane = tid & 63;
    const int g = lane >> 4, lr = lane & 15;
    const size_t base = (size_t)bh * SEQ;
    const float L2E = 1.4426950408889634f;
    const bf16* vb = vat + (size_t)bh * DHD * SEQ;

    uint4 kreg0, kreg1, kreg2, vreg0, vreg1;
    const int vd = tid >> 2, vko = (tid & 3) * 16;
    const int kr0 = tid / 12,          ks0 = tid % 12;
    const int kr1 = (tid + 256) / 12,  ks1 = (tid + 256) % 12;
    const int kr2 = (tid + 512) / 12,  ks2 = (tid + 512) % 12;
    const int kx0 = (ks0 ^ (kr0 & 15)) * 8;
    const int kx1 = (ks1 ^ (kr1 & 15)) * 8;
    const int kx2 = (ks2 ^ (kr2 & 15)) * 8;

    #define ISSUE_KV(j0)  do { \
        kreg0 = *(const uint4*)&ka[(base + (j0) + kr0) * DQKPAD + ks0 * 8]; \
        kreg1 = *(const uint4*)&ka[(base + (j0) + kr1) * DQKPAD + ks1 * 8]; \
        kreg2 = *(const uint4*)&ka[(base + (j0) + kr2) * DQKPAD + ks2 * 8]; \
        const bf16* vsrc = &vb[(size_t)vd * SEQ + (j0) + vko]; \
        vreg0 = *(const uint4*)vsrc; vreg1 = *(const uint4*)(vsrc + 8); \
    } while (0)

    for (int half = 0; half < 2; ++half) {
        const int qb = half ? (31 - pr) : pr;
        const int qrow0 = qb * 64 + w * 16;
        const int myq = qrow0 + lr;

        bf16x8 qf[3];
        #pragma unroll
        for (int kc = 0; kc < 3; ++kc)
            qf[kc] = ld_bf8(&qa[(base + myq) * DQKPAD + kc * 32 + g * 8]);

        float m_p = -1e30f, l_p = 0.f;
        f32x4 acc_o[4] = {};
        const int ng = qb + 1;
        const int bs = (ng * sp) >> 2, be = (ng * (sp + 1)) >> 2;

        if (bs < be) ISSUE_KV(bs * 64);

        for (int gi = bs; gi < be; ++gi) {
            const int j0 = gi * 64;
            __syncthreads();
            *(uint4*)&Kl[kr0][kx0] = kreg0;
            *(uint4*)&Kl[kr1][kx1] = kreg1;
            *(uint4*)&Kl[kr2][kx2] = kreg2;
            *(uint4*)&Vt[vd][vko]     = vreg0;
            *(uint4*)&Vt[vd][vko + 8] = vreg1;
            __syncthreads();
            if (gi + 1 < be) ISSUE_KV(j0 + 64);

            f32x4 accs[4] = {};
            __builtin_amdgcn_s_setprio(1);
            #pragma unroll
            for (int kc = 0; kc < 3; ++kc) {
                #pragma unroll
                for (int nt = 0; nt < 4; ++nt) {
                    bf16x8 kf = ld_bf8(&Kl[nt * 16 + lr][((kc * 4 + g) ^ lr) * 8]);
                    accs[nt] = __builtin_amdgcn_mfma_f32_16x16x32_bf16(kf, qf[kc], accs[nt], 0, 0, 0);
                }
            }
            __builtin_amdgcn_s_setprio(0);
            float s_[4][4];
            float mloc = -1e30f;
            if (j0 + 63 > qrow0) {
                #pragma unroll
                for (int nt = 0; nt < 4; ++nt)
                #pragma unroll
                for (int r = 0; r < 4; ++r) {
                    int key = j0 + nt * 16 + g * 4 + r;
                    float sv = accs[nt][r];
                    sv = (key <= myq) ? sv : -1e30f;
                    s_[nt][r] = sv;
                    mloc = fmaxf(mloc, sv);
                }
            } else {
                #pragma unroll
                for (int nt = 0; nt < 4; ++nt)
                #pragma unroll
                for (int r = 0; r < 4; ++r) {
                    float sv = accs[nt][r];
                    s_[nt][r] = sv;
                    mloc = fmaxf(mloc, sv);
                }
            }
            mloc = fmaxf(mloc, __shfl_xor(mloc, 16));
            mloc = fmaxf(mloc, __shfl_xor(mloc, 32));

            if (__all(mloc <= m_p + 8.f)) {
                float rs = 0.f;
                #pragma unroll
                for (int nt = 0; nt < 4; ++nt)
                #pragma unroll
                for (int r = 0; r < 4; ++r) {
                    float p = exp2f((s_[nt][r] - m_p) * L2E);
                    s_[nt][r] = p; rs += p;
                }
                rs += __shfl_xor(rs, 16);
                rs += __shfl_xor(rs, 32);
                l_p += rs;
            } else {
                float mn = fmaxf(m_p, mloc);
                float alpha = exp2f((m_p - mn) * L2E);
                m_p = mn;
                float rs = 0.f;
                #pragma unroll
                for (int nt = 0; nt < 4; ++nt)
                #pragma unroll
                for (int r = 0; r < 4; ++r) {
                    float p = exp2f((s_[nt][r] - mn) * L2E);
                    s_[nt][r] = p; rs += p;
                }
                rs += __shfl_xor(rs, 16);
                rs += __shfl_xor(rs, 32);
                l_p = l_p * alpha + rs;
                float ar[4];
                #pragma unroll
                for (int r = 0; r < 4; ++r) ar[r] = __shfl(alpha, g * 4 + r);
                #pragma unroll
                for (int nv = 0; nv < 4; ++nv)
                #pragma unroll
                for (int r = 0; r < 4; ++r) acc_o[nv][r] *= ar[r];
            }
            #pragma unroll
            for (int nt = 0; nt < 4; ++nt) {
                ushort4 pk;
                pk.x = __builtin_bit_cast(u16, __float2bfloat16(s_[nt][0]));
                pk.y = __builtin_bit_cast(u16, __float2bfloat16(s_[nt][1]));
                pk.z = __builtin_bit_cast(u16, __float2bfloat16(s_[nt][2]));
                pk.w = __builtin_bit_cast(u16, __float2bfloat16(s_[nt][3]));
                *(ushort4*)&Pl[w][lr][nt * 16 + g * 4] = pk;
            }
            bf16x8 pf0 = ld_bf8(&Pl[w][lr][g * 8]);
            bf16x8 pf1 = ld_bf8(&Pl[w][lr][32 + g * 8]);
            __builtin_amdgcn_s_setprio(1);
            #pragma unroll
            for (int nv = 0; nv < 4; ++nv) {
                bf16x8 vf0 = ld_bf8(&Vt[nv * 16 + lr][g * 8]);
                acc_o[nv] = __builtin_amdgcn_mfma_f32_16x16x32_bf16(pf0, vf0, acc_o[nv], 0, 0, 0);
                bf16x8 vf1 = ld_bf8(&Vt[nv * 16 + lr][32 + g * 8]);
                acc_o[nv] = __builtin_amdgcn_mfma_f32_16x16x32_bf16(pf1, vf1, acc_o[nv], 0, 0, 0);
            }
            __builtin_amdgcn_s_setprio(0);
        }

        const size_t pb = (size_t)(bh * NSPLIT + sp) * SEQ;
        #pragma unroll
        for (int r = 0; r < 4; ++r) {
            int qrow = qrow0 + g * 4 + r;
            #pragma unroll
            for (int nv = 0; nv < 4; ++nv)
                po[(pb + qrow) * DHD + nv * 16 + lr] = __float2bfloat16(acc_o[nv][r]);
        }
        if (lane < 16) {
            size_t mi = ((size_t)bh * SEQ + qrow0 + lane) * 4 + sp;
            mlm[mi] = m_p;
            mll[mi] = l_p;
        }
    }
    #undef ISSUE_KV
}

// ---------------- combine split partials -> attn_o [b][s][h*64+d] ----------------
__global__ __launch_bounds__(256) void attn_combine(
    const bf16* __restrict__ po, const float* __restrict__ mlm, const float* __restrict__ mll,
    bf16* __restrict__ ao)
{
    int id = blockIdx.x * 256 + threadIdx.x;   // 16*2048*8 = 262144
    int bh = id >> 14;
    int rem = id & 16383;
    int q = rem >> 3, dc = (rem & 7) * 8;
    const float L2E = 1.4426950408889634f;
    size_t mi = ((size_t)bh * SEQ + q) * 4;
    f32x4 ms = *(const f32x4*)&mlm[mi];
    f32x4 ls = *(const f32x4*)&mll[mi];
    float M = fmaxf(fmaxf(ms[0], ms[1]), fmaxf(ms[2], ms[3]));
    float wsc[NSPLIT]; float L = 0.f;
    #pragma unroll
    for (int s = 0; s < NSPLIT; ++s) { wsc[s] = exp2f((ms[s] - M) * L2E); L += wsc[s] * ls[s]; }
    float o[8] = {};
    #pragma unroll
    for (int s = 0; s < NSPLIT; ++s) {
        if (ls[s] <= 0.f) continue;
        bf16x8 pv = ld_bf8(&po[((size_t)(bh * NSPLIT + s) * SEQ + q) * DHD + dc]);
        #pragma unroll
        for (int j = 0; j < 8; ++j) o[j] += wsc[s] * (float)pv[j];
    }
    float invL = 1.f / L;
    int b = bh >> 3, h = bh & 7;
    __bf16 tmp[8];
    #pragma unroll
    for (int j = 0; j < 8; ++j) tmp[j] = (__bf16)(o[j] * invL);
    *(uint4*)&ao[((size_t)(b * SEQ) + q) * DM + h * DHD + dc] = *(uint4*)tmp;
}

extern "C" void kernel_launch(void* const* d_in, const int* in_sizes, int n_in,
                              void* d_out, int out_size, void* d_ws, size_t ws_size,
                              hipStream_t stream) {
    char* ws = (char*)d_ws;
    bf16* AR      = (bf16*)(ws + 0);              // arena: x | W_o | params
    float* ml_m   = (float*)(ws + 0);             // alias x region (dead after x-gemm), 512KB
    float* ml_l   = (float*)(ws + 1048576);       // 512KB
    bf16* WT      = (bf16*)(ws + 6391296);        // transposed weights (1,802,240 B)
    int*  flagp   = (int*)(ws + 8193536);
    bf16* y       = (bf16*)(ws + 8194048);        // fused x-proj out [4096][704] bf16
    bf16* cq      = (bf16*)(ws + 19728384);       // [4096][256]
    bf16* ckvp    = (bf16*)(ws + 21825536);       // [4096][384]
    bf16* q_attn  = (bf16*)(ws + 26019840);
    bf16* k_attn  = (bf16*)(ws + 32311296);
    bf16* v_attnT = (bf16*)(ws + 38602752);
    bf16* attn_o  = (bf16*)(ws + 42797056);
    bf16* po      = (bf16*)(ws + 50331648);       // 4-split partials, 16,777,216 B

    const bf16* xb  = AR + OFF_X;
    const bf16* W_o = AR + OFF_WO;
    const bf16* qg  = AR + OFF_QG;
    const bf16* qb_ = AR + OFF_QB;
    const bf16* kg  = AR + OFF_KG;
    const bf16* kb  = AR + OFF_KB;

    bf16*  out_b = (bf16*)d_out;
    float* out_f = (float*)d_out;
    bf16*  ckv_b = out_b + (size_t)MROWS * DM;
    float* ckv_f = out_f + (size_t)MROWS * DM;

    dim3 blk(256);
    // 1) prep: flag + convert + weight transposes (8-wide)
    prep<<<dim3((G_TOT + 255) / 256), blk, 0, stream>>>(
        d_in[0], d_in[1], d_in[2], d_in[3], d_in[4], d_in[5],
        d_in[6], d_in[7], d_in[8], d_in[9], d_in[10], d_in[11],
        (u16*)AR, (u16*)WT, flagp);
    // 2) fused x-proj [dq|dkv|kr] N=704, bf16 y (n0==640 block does kr-rope -> k_attn)
    gemm128<<<dim3(11, 32), blk, 0, stream>>>(xb, DM, WT + T_DQ, DM, 704, DM, 0, y, 704, k_attn, nullptr, nullptr, nullptr);
    // 3) merged layernorms (bf16 y in)
    ln_both<<<dim3(2048), blk, 0, stream>>>(y, qg, qb_, kg, kb, cq, ckv_b, ckv_f, ckvp, flagp);
    // 4+5) merged up-projections: uq (q-rope) + ukv (K/V^T scatter)
    gemm_dual<<<dim3(25, 32), blk, 0, stream>>>(cq, WT + T_UQ, q_attn, ckvp, WT + T_UKV, k_attn, v_attnT);
    // 6) attention (4-way split-KV, qb-paired, swapped-softmax, defer-max, T14, T2, T5)
    attn_split3<<<dim3(NSPLIT, 16, 16), blk, 0, stream>>>(q_attn, k_attn, v_attnT, po, ml_m, ml_l);
    // 7) combine (float4 m/l)
    attn_combine<<<dim3(1024), blk, 0, stream>>>(po, ml_m, ml_l, attn_o);
    // 8) output projection -> d_out (dual dtype)
    gemm128<<<dim3(8, 32), blk, 0, stream>>>(attn_o, DM, W_o, DM, DM, DM, 1, out_b, DM, nullptr, nullptr, flagp, out_f);
}